// Round 1
// baseline (2814.483 us; speedup 1.0000x reference)
//
#include <hip/hip_runtime.h>

// HetSAGE: 2-layer heterogeneous GraphSAGE on bipartite user/item graph.
// N=50000 nodes/type, E=500000 edges/type, D=256, ED=32.
//
// Strategy:
//  - add_i/add_u (edge-time bias) via linearity: scatter-sum raw 32-dim edge
//    feats, fold the (32->256) MLP into the fused GEMM as 32 extra K columns.
//  - mean aggregation via CSR (count -> scan -> fill) + gather-sum. No f32
//    atomics, no agg zeroing (full row written each time).
//  - fused kernel: y = [h_self | agg_mean | et_mean] @ [W ; Wem] + b +
//    bem*[cnt>0], then LayerNorm. Row-local => layer 1 updates d_out in place.

#define ND_NODES 50000
#define DDIM 256
#define EDIM 32
#define TWO_D 512
#define XK (TWO_D + EDIM)   // 544
#define NB 8                // nodes per fused block

__global__ void count_kernel(const int* __restrict__ dst, int E, int* __restrict__ cnt) {
    int e = blockIdx.x * blockDim.x + threadIdx.x;
    if (e < E) atomicAdd(&cnt[dst[e]], 1);
}

// single-block exclusive scan of cnt[0..n) -> rowstart[0..n], cursor copy
__global__ void scan_kernel(const int* __restrict__ cnt, int* __restrict__ rowstart,
                            int* __restrict__ cursor, int n) {
    __shared__ int sums[1024];
    const int PER = (ND_NODES + 1023) / 1024;  // 49
    int tid = threadIdx.x;
    int base = tid * PER;
    int s = 0;
    for (int i = 0; i < PER; ++i) {
        int idx = base + i;
        if (idx < n) s += cnt[idx];
    }
    sums[tid] = s;
    __syncthreads();
    for (int off = 1; off < 1024; off <<= 1) {
        int v = 0;
        if (tid >= off) v = sums[tid - off];
        __syncthreads();
        if (tid >= off) sums[tid] += v;
        __syncthreads();
    }
    int run = (tid > 0) ? sums[tid - 1] : 0;
    for (int i = 0; i < PER; ++i) {
        int idx = base + i;
        if (idx < n) {
            rowstart[idx] = run;
            cursor[idx]   = run;
            run += cnt[idx];
        }
    }
    if (tid == 1023) rowstart[n] = sums[1023];
}

__global__ void fill_kernel(const int* __restrict__ src, const int* __restrict__ dst, int E,
                            int* __restrict__ cursor, int* __restrict__ ssrc) {
    int e = blockIdx.x * blockDim.x + threadIdx.x;
    if (e < E) {
        int d = dst[e];
        int p = atomicAdd(&cursor[d], 1);
        ssrc[p] = src[e];
    }
}

__global__ void etscatter_kernel(const float* __restrict__ et, const int* __restrict__ dst,
                                 int E, float* __restrict__ etsum) {
    int idx = blockIdx.x * blockDim.x + threadIdx.x;
    if (idx < E * EDIM) {
        int e = idx >> 5;
        int c = idx & (EDIM - 1);
        atomicAdd(&etsum[(size_t)dst[e] * EDIM + c], et[idx]);
    }
}

// one block (256 thr) per dst node: agg[node][t] = sum over in-edges of h[src][t]
__global__ void agg_gather_kernel(const float* __restrict__ h, const int* __restrict__ rowstart,
                                  const int* __restrict__ ssrc, float* __restrict__ agg) {
    int node = blockIdx.x;
    int t = threadIdx.x;
    int s0 = rowstart[node], s1 = rowstart[node + 1];
    float acc = 0.f;
    for (int e = s0; e < s1; ++e) {
        int s = ssrc[e];
        acc += h[(size_t)s * DDIM + t];
    }
    agg[(size_t)node * DDIM + t] = acc;  // raw sum; /cnt happens in fused load
}

// fused: out[n] = LN( [hself | agg/cnt | etsum/cnt] @ [W;Wem] + b + bem*[cnt>0] )
// 64 threads, NB nodes/block; lane t owns dims {t, t+64, t+128, t+192}.
__global__ __launch_bounds__(64) void fused_kernel(
    const float* __restrict__ hself, const float* __restrict__ agg,
    const float* __restrict__ etsum, const int* __restrict__ cnt,
    const float* __restrict__ W, const float* __restrict__ b,
    const float* __restrict__ Wem, const float* __restrict__ bem,
    const float* __restrict__ g, const float* __restrict__ beta,
    float* __restrict__ out, int n) {
    __shared__ float xs[NB][XK];
    int t = threadIdx.x;
    int n0 = blockIdx.x * NB;

    float ind[NB];
    for (int j = 0; j < NB; ++j) {
        int node = n0 + j;
        if (node < n) {
            int c = cnt[node];
            float ic = 1.0f / (float)(c > 1 ? c : 1);
            ind[j] = (c > 0) ? 1.0f : 0.0f;
            for (int cc = t; cc < DDIM; cc += 64) {
                xs[j][cc]        = hself[(size_t)node * DDIM + cc];
                xs[j][DDIM + cc] = agg[(size_t)node * DDIM + cc] * ic;
            }
            if (t < EDIM) xs[j][TWO_D + t] = etsum[(size_t)node * EDIM + t] * ic;
        } else {
            ind[j] = 0.f;
            for (int cc = t; cc < XK; cc += 64) xs[j][cc] = 0.f;
        }
    }
    __syncthreads();

    float acc[4][NB];
#pragma unroll
    for (int dd = 0; dd < 4; ++dd)
#pragma unroll
        for (int j = 0; j < NB; ++j) acc[dd][j] = 0.f;

    const float* wp = W + t;
    for (int k = 0; k < TWO_D; k += 4) {
        float w[4][4];
#pragma unroll
        for (int kk = 0; kk < 4; ++kk)
#pragma unroll
            for (int dd = 0; dd < 4; ++dd)
                w[kk][dd] = wp[(size_t)(k + kk) * DDIM + dd * 64];
#pragma unroll
        for (int j = 0; j < NB; ++j) {
            float4 xv = *reinterpret_cast<const float4*>(&xs[j][k]);
#pragma unroll
            for (int dd = 0; dd < 4; ++dd)
                acc[dd][j] += xv.x * w[0][dd] + xv.y * w[1][dd]
                            + xv.z * w[2][dd] + xv.w * w[3][dd];
        }
    }
    const float* wemp = Wem + t;
    for (int k = 0; k < EDIM; k += 4) {
        float w[4][4];
#pragma unroll
        for (int kk = 0; kk < 4; ++kk)
#pragma unroll
            for (int dd = 0; dd < 4; ++dd)
                w[kk][dd] = wemp[(size_t)(k + kk) * DDIM + dd * 64];
#pragma unroll
        for (int j = 0; j < NB; ++j) {
            float4 xv = *reinterpret_cast<const float4*>(&xs[j][TWO_D + k]);
#pragma unroll
            for (int dd = 0; dd < 4; ++dd)
                acc[dd][j] += xv.x * w[0][dd] + xv.y * w[1][dd]
                            + xv.z * w[2][dd] + xv.w * w[3][dd];
        }
    }

    float bd[4], bemd[4], gd[4], betad[4];
#pragma unroll
    for (int dd = 0; dd < 4; ++dd) {
        int d = t + dd * 64;
        bd[dd] = b[d]; bemd[dd] = bem[d]; gd[dd] = g[d]; betad[dd] = beta[d];
    }

    for (int j = 0; j < NB; ++j) {
        int node = n0 + j;
        float v[4];
#pragma unroll
        for (int dd = 0; dd < 4; ++dd)
            v[dd] = acc[dd][j] + bd[dd] + ind[j] * bemd[dd];
        float s = v[0] + v[1] + v[2] + v[3];
#pragma unroll
        for (int off = 1; off < 64; off <<= 1) s += __shfl_xor(s, off);
        float mean = s * (1.0f / 256.0f);
        float q = 0.f;
#pragma unroll
        for (int dd = 0; dd < 4; ++dd) {
            float dv = v[dd] - mean;
            q += dv * dv;
        }
#pragma unroll
        for (int off = 1; off < 64; off <<= 1) q += __shfl_xor(q, off);
        float inv = rsqrtf(q * (1.0f / 256.0f) + 1e-5f);
        if (node < n) {
#pragma unroll
            for (int dd = 0; dd < 4; ++dd)
                out[(size_t)node * DDIM + t + dd * 64] =
                    (v[dd] - mean) * inv * gd[dd] + betad[dd];
        }
    }
}

static inline size_t alignup(size_t x) { return (x + 1023) & ~(size_t)1023; }

extern "C" void kernel_launch(void* const* d_in, const int* in_sizes, int n_in,
                              void* d_out, int out_size, void* d_ws, size_t ws_size,
                              hipStream_t stream) {
    const float* h_user  = (const float*)d_in[0];
    const float* h_item  = (const float*)d_in[1];
    const float* et_ub   = (const float*)d_in[2];
    const float* et_bu   = (const float*)d_in[3];
    const float* W0_ub   = (const float*)d_in[4];
    const float* b0_ub   = (const float*)d_in[5];
    const float* W0_bu   = (const float*)d_in[6];
    const float* b0_bu   = (const float*)d_in[7];
    const float* W1_ub   = (const float*)d_in[8];
    const float* b1_ub   = (const float*)d_in[9];
    const float* W1_bu   = (const float*)d_in[10];
    const float* b1_bu   = (const float*)d_in[11];
    const float* Wem_ub  = (const float*)d_in[12];
    const float* bem_ub  = (const float*)d_in[13];
    const float* Wem_bu  = (const float*)d_in[14];
    const float* bem_bu  = (const float*)d_in[15];
    const float* g_u     = (const float*)d_in[16];
    const float* beta_u  = (const float*)d_in[17];
    const float* g_i     = (const float*)d_in[18];
    const float* beta_i  = (const float*)d_in[19];
    const int*   ei_ub   = (const int*)d_in[20];
    const int*   ei_bu   = (const int*)d_in[21];

    const int E = in_sizes[20] / 2;        // 500000
    const int n = in_sizes[0] / DDIM;      // 50000

    // workspace carve-up
    char* w = (char*)d_ws;
    size_t off = 0;
    auto take = [&](size_t bytes) -> void* {
        void* p = w + off;
        off = alignup(off + bytes);
        return p;
    };
    int*   cnt_ub   = (int*)take((size_t)n * 4);
    int*   cnt_bu   = (int*)take((size_t)n * 4);
    float* etsum_ub = (float*)take((size_t)n * EDIM * 4);
    float* etsum_bu = (float*)take((size_t)n * EDIM * 4);
    size_t zero_bytes = off;  // cnt + etsum need zeroing each call
    int*   rs_ub    = (int*)take((size_t)(n + 1) * 4);
    int*   rs_bu    = (int*)take((size_t)(n + 1) * 4);
    int*   cur_ub   = (int*)take((size_t)n * 4);
    int*   cur_bu   = (int*)take((size_t)n * 4);
    int*   ssrc_ub  = (int*)take((size_t)E * 4);
    int*   ssrc_bu  = (int*)take((size_t)E * 4);
    float* aggI     = (float*)take((size_t)n * DDIM * 4);
    float* aggU     = (float*)take((size_t)n * DDIM * 4);
    (void)ws_size; (void)n_in; (void)out_size;

    const int* src_ub = ei_ub;
    const int* dst_ub = ei_ub + E;
    const int* src_bu = ei_bu;
    const int* dst_bu = ei_bu + E;

    hipMemsetAsync(w, 0, zero_bytes, stream);

    int eb = (E + 255) / 256;
    count_kernel<<<eb, 256, 0, stream>>>(dst_ub, E, cnt_ub);
    count_kernel<<<eb, 256, 0, stream>>>(dst_bu, E, cnt_bu);
    scan_kernel<<<1, 1024, 0, stream>>>(cnt_ub, rs_ub, cur_ub, n);
    scan_kernel<<<1, 1024, 0, stream>>>(cnt_bu, rs_bu, cur_bu, n);
    fill_kernel<<<eb, 256, 0, stream>>>(src_ub, dst_ub, E, cur_ub, ssrc_ub);
    fill_kernel<<<eb, 256, 0, stream>>>(src_bu, dst_bu, E, cur_bu, ssrc_bu);
    int etb = (E * EDIM + 255) / 256;
    etscatter_kernel<<<etb, 256, 0, stream>>>(et_ub, dst_ub, E, etsum_ub);
    etscatter_kernel<<<etb, 256, 0, stream>>>(et_bu, dst_bu, E, etsum_bu);

    float* hu_out = (float*)d_out;
    float* hi_out = (float*)d_out + (size_t)n * DDIM;
    int fb = (n + NB - 1) / NB;

    // layer 0 (reads pristine inputs)
    agg_gather_kernel<<<n, 256, 0, stream>>>(h_user, rs_ub, ssrc_ub, aggI);
    agg_gather_kernel<<<n, 256, 0, stream>>>(h_item, rs_bu, ssrc_bu, aggU);
    fused_kernel<<<fb, 64, 0, stream>>>(h_item, aggI, etsum_ub, cnt_ub,
                                        W0_ub, b0_ub, Wem_ub, bem_ub,
                                        g_i, beta_i, hi_out, n);
    fused_kernel<<<fb, 64, 0, stream>>>(h_user, aggU, etsum_bu, cnt_bu,
                                        W0_bu, b0_bu, Wem_bu, bem_bu,
                                        g_u, beta_u, hu_out, n);

    // layer 1: both gathers first (they read old hu/hi globally), then the
    // fused kernels update d_out in place (row-local reads/writes only).
    agg_gather_kernel<<<n, 256, 0, stream>>>(hu_out, rs_ub, ssrc_ub, aggI);
    agg_gather_kernel<<<n, 256, 0, stream>>>(hi_out, rs_bu, ssrc_bu, aggU);
    fused_kernel<<<fb, 64, 0, stream>>>(hi_out, aggI, etsum_ub, cnt_ub,
                                        W1_ub, b1_ub, Wem_ub, bem_ub,
                                        g_i, beta_i, hi_out, n);
    fused_kernel<<<fb, 64, 0, stream>>>(hu_out, aggU, etsum_bu, cnt_bu,
                                        W1_bu, b1_bu, Wem_bu, bem_bu,
                                        g_u, beta_u, hu_out, n);
}

// Round 2
// 918.417 us; speedup vs baseline: 3.0645x; 3.0645x over previous
//
#include <hip/hip_runtime.h>

// HetSAGE: 2-layer heterogeneous GraphSAGE, N=50000/type, E=500000/type, D=256.
// This round: bf16 MFMA GEMM (16x16x32), packed X=[self|agg|et] (K=544),
// W pre-transposed, global_load_lds staging with XOR-swizzled source,
// fused bias+LayerNorm epilogue.

#define DDIM 256
#define EDIM 32
#define XK 544          // 512 + 32
#define BM 128          // GEMM row tile
#define KC 32           // K chunk (one MFMA k-slice)
#define KSTEPS 17       // 544/32

typedef unsigned short u16;
typedef short s16x8 __attribute__((ext_vector_type(8)));
typedef float f32x4 __attribute__((ext_vector_type(4)));
typedef u16 u16x4 __attribute__((ext_vector_type(4)));

__device__ __forceinline__ u16 f2bf(float f) {
    unsigned u = __builtin_bit_cast(unsigned, f);
    u += 0x7FFF + ((u >> 16) & 1);           // RNE
    return (u16)(u >> 16);
}
__device__ __forceinline__ float bf2f(u16 u) {
    unsigned x = ((unsigned)u) << 16;
    return __builtin_bit_cast(float, x);
}

#define GLOAD16(gp, lp)                                                        \
    __builtin_amdgcn_global_load_lds(                                          \
        (const __attribute__((address_space(1))) unsigned int*)(gp),           \
        (__attribute__((address_space(3))) unsigned int*)(lp), 16, 0, 0)

// ---------------- CSR build (unchanged, proven) ----------------
__global__ void count_kernel(const int* __restrict__ dst, int E, int* __restrict__ cnt) {
    int e = blockIdx.x * blockDim.x + threadIdx.x;
    if (e < E) atomicAdd(&cnt[dst[e]], 1);
}

__global__ void scan_kernel(const int* __restrict__ cnt, int* __restrict__ rowstart,
                            int* __restrict__ cursor, int n) {
    __shared__ int sums[1024];
    const int PER = (50000 + 1023) / 1024;
    int tid = threadIdx.x;
    int base = tid * PER;
    int s = 0;
    for (int i = 0; i < PER; ++i) {
        int idx = base + i;
        if (idx < n) s += cnt[idx];
    }
    sums[tid] = s;
    __syncthreads();
    for (int off = 1; off < 1024; off <<= 1) {
        int v = 0;
        if (tid >= off) v = sums[tid - off];
        __syncthreads();
        if (tid >= off) sums[tid] += v;
        __syncthreads();
    }
    int run = (tid > 0) ? sums[tid - 1] : 0;
    for (int i = 0; i < PER; ++i) {
        int idx = base + i;
        if (idx < n) {
            rowstart[idx] = run;
            cursor[idx]   = run;
            run += cnt[idx];
        }
    }
    if (tid == 1023) rowstart[n] = sums[1023];
}

__global__ void fill_kernel(const int* __restrict__ src, const int* __restrict__ dst, int E,
                            int* __restrict__ cursor, int* __restrict__ ssrc) {
    int e = blockIdx.x * blockDim.x + threadIdx.x;
    if (e < E) {
        int d = dst[e];
        int p = atomicAdd(&cursor[d], 1);
        ssrc[p] = src[e];
    }
}

__global__ void etscatter_kernel(const float* __restrict__ et, const int* __restrict__ dst,
                                 int E, float* __restrict__ etsum) {
    int idx = blockIdx.x * blockDim.x + threadIdx.x;
    if (idx < E * EDIM) {
        int e = idx >> 5;
        int c = idx & (EDIM - 1);
        atomicAdd(&etsum[(size_t)dst[e] * EDIM + c], et[idx]);
    }
}

// ---------------- bf16 prep ----------------
__global__ void conv_h_kernel(const float* __restrict__ h, u16* __restrict__ hb, int total4) {
    int i = blockIdx.x * blockDim.x + threadIdx.x;
    int stride = gridDim.x * blockDim.x;
    for (; i < total4; i += stride) {
        float4 v = reinterpret_cast<const float4*>(h)[i];
        u16x4 o;
        o.x = f2bf(v.x); o.y = f2bf(v.y); o.z = f2bf(v.z); o.w = f2bf(v.w);
        reinterpret_cast<u16x4*>(hb)[i] = o;
    }
}

// WT[mat][c][k] = (k<512 ? W[k][c] : Wem[k-512][c]) as bf16
__global__ void wt_build_kernel(const float* W0, const float* W1, const float* W2,
                                const float* W3, const float* EmA, const float* EmB,
                                u16* __restrict__ WT) {
    int k = blockIdx.x;           // 0..543
    int mat = blockIdx.y;         // 0..3
    int c = threadIdx.x;          // 0..255
    const float* W = (mat == 0) ? W0 : (mat == 1) ? W1 : (mat == 2) ? W2 : W3;
    const float* Em = (mat & 1) ? EmB : EmA;
    float v = (k < 512) ? W[(size_t)k * DDIM + c] : Em[(size_t)(k - 512) * DDIM + c];
    WT[((size_t)mat * DDIM + c) * XK + k] = f2bf(v);
}

// X row = [bf16(self) | bf16(mean agg) | bf16(mean et)], one 64-thr wave/node
__global__ __launch_bounds__(64) void build_x_kernel(
    const u16* __restrict__ hbself, const u16* __restrict__ hbsrc,
    const int* __restrict__ rs, const int* __restrict__ ssrc,
    const float* __restrict__ etsum, u16* __restrict__ XB) {
    int node = blockIdx.x;
    int t = threadIdx.x;
    int s0 = rs[node], s1 = rs[node + 1];
    int c = s1 - s0;
    float ic = 1.0f / (float)(c > 1 ? c : 1);
    float a0 = 0.f, a1 = 0.f, a2 = 0.f, a3 = 0.f;
    for (int e = s0; e < s1; ++e) {
        int s = ssrc[e];
        u16x4 v = *reinterpret_cast<const u16x4*>(&hbsrc[(size_t)s * DDIM + t * 4]);
        a0 += bf2f(v.x); a1 += bf2f(v.y); a2 += bf2f(v.z); a3 += bf2f(v.w);
    }
    u16* xr = XB + (size_t)node * XK;
    *reinterpret_cast<u16x4*>(&xr[t * 4]) =
        *reinterpret_cast<const u16x4*>(&hbself[(size_t)node * DDIM + t * 4]);
    u16x4 o;
    o.x = f2bf(a0 * ic); o.y = f2bf(a1 * ic); o.z = f2bf(a2 * ic); o.w = f2bf(a3 * ic);
    *reinterpret_cast<u16x4*>(&xr[DDIM + t * 4]) = o;
    if (t < EDIM) xr[512 + t] = f2bf(etsum[(size_t)node * EDIM + t] * ic);
}

// ---------------- MFMA GEMM + bias + LayerNorm ----------------
// out[r][c] = LN( XB[r][:] @ WT[c][:] + b[c] + ind[r]*bem[c] ) * g[c] + beta[c]
// block: 512 thr (8 waves, 2Mx4N), tile 128x256, K=544 in 17 steps of 32.
__global__ __launch_bounds__(512) void gemm_ln_kernel(
    const u16* __restrict__ XB, const u16* __restrict__ WT,
    const float* __restrict__ bvec, const float* __restrict__ bem,
    const int* __restrict__ rs,
    const float* __restrict__ g, const float* __restrict__ beta,
    float* __restrict__ out, int n) {
    __shared__ u16 Al[2 * BM * KC];          // 16 KB
    __shared__ u16 Bl[2 * DDIM * KC];        // 32 KB
    __shared__ float2 mom[BM][4];            // 4 KB
    __shared__ float indls[BM];

    const int t = threadIdx.x;
    const int wid = t >> 6, lane = t & 63, lo = lane & 15, hi = lane >> 4;
    const int wr = wid >> 2, wc = wid & 3;
    const int n0 = blockIdx.x * BM;

    if (t < BM) {
        int r = n0 + t;
        indls[t] = (r < n && (rs[r + 1] - rs[r]) > 0) ? 1.0f : 0.0f;
    }

    // staging source addresses (inverse-swizzled global; LDS dest is linear)
    const int arow = t >> 2;
    const int aslot = (t & 3) ^ ((arow >> 1) & 3);
    const u16* agp = XB + (size_t)(n0 + arow) * XK + aslot * 8;
    const int br0 = t >> 2;
    const int bs0 = (t & 3) ^ ((br0 >> 1) & 3);
    const u16* bgp0 = WT + (size_t)br0 * XK + bs0 * 8;
    const int br1 = 128 + (t >> 2);
    const int bs1 = (t & 3) ^ ((br1 >> 1) & 3);
    const u16* bgp1 = WT + (size_t)br1 * XK + bs1 * 8;

    f32x4 acc[4][4];
#pragma unroll
    for (int i = 0; i < 4; ++i)
#pragma unroll
        for (int j = 0; j < 4; ++j) acc[i][j] = {0.f, 0.f, 0.f, 0.f};

    auto STAGE = [&](int buf, int kk) {
        int k0 = kk * KC;
        GLOAD16(agp + k0, &Al[buf * 4096 + wid * 512]);
        GLOAD16(bgp0 + k0, &Bl[buf * 8192 + wid * 512]);
        GLOAD16(bgp1 + k0, &Bl[buf * 8192 + 4096 + wid * 512]);
    };

    STAGE(0, 0);
    __syncthreads();

    for (int ks = 0; ks < KSTEPS; ++ks) {
        int cur = ks & 1;
        if (ks < KSTEPS - 1) STAGE(1 - cur, ks + 1);  // in-flight across compute

        s16x8 af[4], bf[4];
#pragma unroll
        for (int rt = 0; rt < 4; ++rt) {
            int row = wr * 64 + rt * 16 + lo;
            af[rt] = *reinterpret_cast<const s16x8*>(
                &Al[cur * 4096 + row * KC + ((hi ^ ((row >> 1) & 3)) << 3)]);
        }
#pragma unroll
        for (int ct = 0; ct < 4; ++ct) {
            int c = wc * 64 + ct * 16 + lo;
            bf[ct] = *reinterpret_cast<const s16x8*>(
                &Bl[cur * 8192 + c * KC + ((hi ^ ((c >> 1) & 3)) << 3)]);
        }
#pragma unroll
        for (int rt = 0; rt < 4; ++rt)
#pragma unroll
            for (int ct = 0; ct < 4; ++ct)
                acc[rt][ct] = __builtin_amdgcn_mfma_f32_16x16x32_bf16(
                    af[rt], bf[ct], acc[rt][ct], 0, 0, 0);

        __syncthreads();  // drains vmcnt (next tile landed) + lgkmcnt; LDS reusable
    }

    // epilogue: bias + ind*bem, then LN over the 256 cols of each row
    float bb[4], bbem[4], gv[4], bev[4];
#pragma unroll
    for (int ct = 0; ct < 4; ++ct) {
        int c = wc * 64 + ct * 16 + lo;
        bb[ct] = bvec[c]; bbem[ct] = bem[c]; gv[ct] = g[c]; bev[ct] = beta[c];
    }
#pragma unroll
    for (int rt = 0; rt < 4; ++rt)
#pragma unroll
        for (int reg = 0; reg < 4; ++reg) {
            float indv = indls[wr * 64 + rt * 16 + hi * 4 + reg];
#pragma unroll
            for (int ct = 0; ct < 4; ++ct)
                acc[rt][ct][reg] += bb[ct] + indv * bbem[ct];
        }

    // per-row partial moments over this wave's 64 cols
#pragma unroll
    for (int rt = 0; rt < 4; ++rt)
#pragma unroll
        for (int reg = 0; reg < 4; ++reg) {
            float s = acc[rt][0][reg] + acc[rt][1][reg] + acc[rt][2][reg] + acc[rt][3][reg];
            float q = acc[rt][0][reg] * acc[rt][0][reg] + acc[rt][1][reg] * acc[rt][1][reg]
                    + acc[rt][2][reg] * acc[rt][2][reg] + acc[rt][3][reg] * acc[rt][3][reg];
#pragma unroll
            for (int m = 1; m < 16; m <<= 1) {
                s += __shfl_xor(s, m);
                q += __shfl_xor(q, m);
            }
            if (lo == 0) mom[wr * 64 + rt * 16 + hi * 4 + reg][wc] = make_float2(s, q);
        }
    __syncthreads();

#pragma unroll
    for (int rt = 0; rt < 4; ++rt)
#pragma unroll
        for (int reg = 0; reg < 4; ++reg) {
            int rl = wr * 64 + rt * 16 + hi * 4 + reg;
            float2 m0 = mom[rl][0], m1 = mom[rl][1], m2 = mom[rl][2], m3 = mom[rl][3];
            float s = m0.x + m1.x + m2.x + m3.x;
            float q = m0.y + m1.y + m2.y + m3.y;
            float mean = s * (1.0f / 256.0f);
            float var = q * (1.0f / 256.0f) - mean * mean;
            float inv = rsqrtf(var + 1e-5f);
            int r = n0 + rl;
            if (r < n) {
#pragma unroll
                for (int ct = 0; ct < 4; ++ct)
                    out[(size_t)r * DDIM + wc * 64 + ct * 16 + lo] =
                        (acc[rt][ct][reg] - mean) * inv * gv[ct] + bev[ct];
            }
        }
}

static inline size_t alignup(size_t x) { return (x + 1023) & ~(size_t)1023; }

extern "C" void kernel_launch(void* const* d_in, const int* in_sizes, int n_in,
                              void* d_out, int out_size, void* d_ws, size_t ws_size,
                              hipStream_t stream) {
    const float* h_user  = (const float*)d_in[0];
    const float* h_item  = (const float*)d_in[1];
    const float* et_ub   = (const float*)d_in[2];
    const float* et_bu   = (const float*)d_in[3];
    const float* W0_ub   = (const float*)d_in[4];
    const float* b0_ub   = (const float*)d_in[5];
    const float* W0_bu   = (const float*)d_in[6];
    const float* b0_bu   = (const float*)d_in[7];
    const float* W1_ub   = (const float*)d_in[8];
    const float* b1_ub   = (const float*)d_in[9];
    const float* W1_bu   = (const float*)d_in[10];
    const float* b1_bu   = (const float*)d_in[11];
    const float* bem_ub  = (const float*)d_in[13];
    const float* bem_bu  = (const float*)d_in[15];
    const float* g_u     = (const float*)d_in[16];
    const float* beta_u  = (const float*)d_in[17];
    const float* g_i     = (const float*)d_in[18];
    const float* beta_i  = (const float*)d_in[19];
    const int*   ei_ub   = (const int*)d_in[20];
    const int*   ei_bu   = (const int*)d_in[21];

    const int E = in_sizes[20] / 2;        // 500000
    const int n = in_sizes[0] / DDIM;      // 50000
    const int nPad = ((n + BM - 1) / BM) * BM;  // 50048

    char* w = (char*)d_ws;
    size_t off = 0;
    auto take = [&](size_t bytes) -> void* {
        void* p = w + off;
        off = alignup(off + bytes);
        return p;
    };
    int*   cnt_ub   = (int*)take((size_t)n * 4);
    int*   cnt_bu   = (int*)take((size_t)n * 4);
    float* etsum_ub = (float*)take((size_t)n * EDIM * 4);
    float* etsum_bu = (float*)take((size_t)n * EDIM * 4);
    size_t zero_bytes = off;
    int*   rs_ub    = (int*)take((size_t)(n + 1) * 4);
    int*   rs_bu    = (int*)take((size_t)(n + 1) * 4);
    int*   cur_ub   = (int*)take((size_t)n * 4);
    int*   cur_bu   = (int*)take((size_t)n * 4);
    int*   ssrc_ub  = (int*)take((size_t)E * 4);
    int*   ssrc_bu  = (int*)take((size_t)E * 4);
    u16*   hbu      = (u16*)take((size_t)n * DDIM * 2);
    u16*   hbi      = (u16*)take((size_t)n * DDIM * 2);
    u16*   XB       = (u16*)take((size_t)nPad * XK * 2);
    u16*   WT       = (u16*)take((size_t)4 * DDIM * XK * 2);
    (void)ws_size; (void)n_in; (void)out_size;

    const int* src_ub = ei_ub;
    const int* dst_ub = ei_ub + E;
    const int* src_bu = ei_bu;
    const int* dst_bu = ei_bu + E;

    hipMemsetAsync(w, 0, zero_bytes, stream);

    int eb = (E + 255) / 256;
    count_kernel<<<eb, 256, 0, stream>>>(dst_ub, E, cnt_ub);
    count_kernel<<<eb, 256, 0, stream>>>(dst_bu, E, cnt_bu);
    scan_kernel<<<1, 1024, 0, stream>>>(cnt_ub, rs_ub, cur_ub, n);
    scan_kernel<<<1, 1024, 0, stream>>>(cnt_bu, rs_bu, cur_bu, n);
    fill_kernel<<<eb, 256, 0, stream>>>(src_ub, dst_ub, E, cur_ub, ssrc_ub);
    fill_kernel<<<eb, 256, 0, stream>>>(src_bu, dst_bu, E, cur_bu, ssrc_bu);
    int etb = (E * EDIM + 255) / 256;
    etscatter_kernel<<<etb, 256, 0, stream>>>(et_ub, dst_ub, E, etsum_ub);
    etscatter_kernel<<<etb, 256, 0, stream>>>(et_bu, dst_bu, E, etsum_bu);

    dim3 wtg(XK, 4);
    wt_build_kernel<<<wtg, 256, 0, stream>>>(W0_ub, W0_bu, W1_ub, W1_bu,
                                             (const float*)d_in[12], (const float*)d_in[14], WT);

    float* hu_out = (float*)d_out;
    float* hi_out = (float*)d_out + (size_t)n * DDIM;
    int total4 = n * DDIM / 4;
    int cvb = 2048;
    int gb = (n + BM - 1) / BM;
    const u16* WT0 = WT;
    const u16* WT1 = WT + (size_t)DDIM * XK;
    const u16* WT2 = WT + (size_t)2 * DDIM * XK;
    const u16* WT3 = WT + (size_t)3 * DDIM * XK;

    // layer 0
    conv_h_kernel<<<cvb, 256, 0, stream>>>(h_user, hbu, total4);
    conv_h_kernel<<<cvb, 256, 0, stream>>>(h_item, hbi, total4);
    build_x_kernel<<<n, 64, 0, stream>>>(hbi, hbu, rs_ub, ssrc_ub, etsum_ub, XB);
    gemm_ln_kernel<<<gb, 512, 0, stream>>>(XB, WT0, b0_ub, bem_ub, rs_ub,
                                           g_i, beta_i, hi_out, n);
    build_x_kernel<<<n, 64, 0, stream>>>(hbu, hbi, rs_bu, ssrc_bu, etsum_bu, XB);
    gemm_ln_kernel<<<gb, 512, 0, stream>>>(XB, WT1, b0_bu, bem_bu, rs_bu,
                                           g_u, beta_u, hu_out, n);

    // layer 1 (snapshots of layer-0 outputs into hb first)
    conv_h_kernel<<<cvb, 256, 0, stream>>>(hi_out, hbi, total4);
    conv_h_kernel<<<cvb, 256, 0, stream>>>(hu_out, hbu, total4);
    build_x_kernel<<<n, 64, 0, stream>>>(hbi, hbu, rs_ub, ssrc_ub, etsum_ub, XB);
    gemm_ln_kernel<<<gb, 512, 0, stream>>>(XB, WT2, b1_ub, bem_ub, rs_ub,
                                           g_i, beta_i, hi_out, n);
    build_x_kernel<<<n, 64, 0, stream>>>(hbu, hbi, rs_bu, ssrc_bu, etsum_bu, XB);
    gemm_ln_kernel<<<gb, 512, 0, stream>>>(XB, WT3, b1_bu, bem_bu, rs_bu,
                                           g_u, beta_u, hu_out, n);
}

// Round 4
// 689.940 us; speedup vs baseline: 4.0793x; 1.3312x over previous
//
#include <hip/hip_runtime.h>

// HetSAGE: 2-layer heterogeneous GraphSAGE, N=50000/type, E=500000/type, D=256.
// R3: fix R2's hbi clobber (layer-0 item gemm no longer writes outbf before
// build_x user consumed original hbi). Multi-block scan + CSR et-gather kept.

#define DDIM 256
#define EDIM 32
#define XK 544          // 512 + 32
#define BM 128          // GEMM row tile
#define KC 32           // K chunk
#define KSTEPS 17       // 544/32
#define SCHUNK 1024     // scan elements per block

typedef unsigned short u16;
typedef short s16x8 __attribute__((ext_vector_type(8)));
typedef float f32x4 __attribute__((ext_vector_type(4)));
typedef u16 u16x4 __attribute__((ext_vector_type(4)));

__device__ __forceinline__ u16 f2bf(float f) {
    unsigned u = __builtin_bit_cast(unsigned, f);
    u += 0x7FFF + ((u >> 16) & 1);           // RNE
    return (u16)(u >> 16);
}
__device__ __forceinline__ float bf2f(u16 u) {
    unsigned x = ((unsigned)u) << 16;
    return __builtin_bit_cast(float, x);
}

#define GLOAD16(gp, lp)                                                        \
    __builtin_amdgcn_global_load_lds(                                          \
        (const __attribute__((address_space(1))) unsigned int*)(gp),           \
        (__attribute__((address_space(3))) unsigned int*)(lp), 16, 0, 0)

// ---------------- CSR build ----------------
__global__ void count_kernel(const int* __restrict__ dst, int E, int* __restrict__ cnt) {
    int e = blockIdx.x * blockDim.x + threadIdx.x;
    if (e < E) atomicAdd(&cnt[dst[e]], 1);
}

// phase A: per-block partial sums (grid: [nb][2], 256 thr, 4 elems/thr)
__global__ void scan_partial_kernel(const int* __restrict__ cnt0, const int* __restrict__ cnt1,
                                    int n, int* __restrict__ bsum, int nb) {
    const int* cnt = blockIdx.y ? cnt1 : cnt0;
    int base = blockIdx.x * SCHUNK + threadIdx.x * 4;
    int s = 0;
#pragma unroll
    for (int i = 0; i < 4; ++i) {
        int idx = base + i;
        if (idx < n) s += cnt[idx];
    }
#pragma unroll
    for (int m = 1; m < 64; m <<= 1) s += __shfl_xor(s, m);
    __shared__ int ws[4];
    int lane = threadIdx.x & 63, wid = threadIdx.x >> 6;
    if (lane == 0) ws[wid] = s;
    __syncthreads();
    if (threadIdx.x == 0) bsum[blockIdx.y * nb + blockIdx.x] = ws[0] + ws[1] + ws[2] + ws[3];
}

// phase B: 1 block, 128 thr; wave w scans type w's nb (<=64) block sums
__global__ void scan_bsum_kernel(int* __restrict__ bsum, int nb,
                                 int* __restrict__ rs0, int* __restrict__ rs1, int n) {
    int wid = threadIdx.x >> 6, lane = threadIdx.x & 63;
    int* bs = bsum + wid * nb;
    int v = (lane < nb) ? bs[lane] : 0;
    int ps = v;
#pragma unroll
    for (int m = 1; m < 64; m <<= 1) {
        int u = __shfl_up(ps, m);
        if (lane >= m) ps += u;
    }
    if (lane < nb) bs[lane] = ps - v;   // exclusive
    if (lane == nb - 1) (wid ? rs1 : rs0)[n] = ps;
}

// phase C: per-block exclusive scan + global offset -> rowstart, cursor
__global__ void scan_final_kernel(const int* __restrict__ cnt0, const int* __restrict__ cnt1,
                                  int n, const int* __restrict__ bsum, int nb,
                                  int* __restrict__ rs0, int* __restrict__ cur0,
                                  int* __restrict__ rs1, int* __restrict__ cur1) {
    const int* cnt = blockIdx.y ? cnt1 : cnt0;
    int* rs  = blockIdx.y ? rs1 : rs0;
    int* cur = blockIdx.y ? cur1 : cur0;
    int t = threadIdx.x;
    int base = blockIdx.x * SCHUNK + t * 4;
    int v[4];
    int s = 0;
#pragma unroll
    for (int i = 0; i < 4; ++i) {
        int idx = base + i;
        v[i] = (idx < n) ? cnt[idx] : 0;
        s += v[i];
    }
    int lane = t & 63, wid = t >> 6;
    int ps = s;
#pragma unroll
    for (int m = 1; m < 64; m <<= 1) {
        int u = __shfl_up(ps, m);
        if (lane >= m) ps += u;
    }
    __shared__ int wsum[4];
    if (lane == 63) wsum[wid] = ps;
    __syncthreads();
    int wofs = 0;
    for (int i = 0; i < wid; ++i) wofs += wsum[i];
    int run = bsum[blockIdx.y * nb + blockIdx.x] + wofs + ps - s;
#pragma unroll
    for (int i = 0; i < 4; ++i) {
        int idx = base + i;
        if (idx < n) {
            rs[idx] = run;
            cur[idx] = run;
            run += v[i];
        }
    }
}

__global__ void fill_kernel(const int* __restrict__ src, const int* __restrict__ dst, int E,
                            int* __restrict__ cursor, int* __restrict__ ssrc,
                            int* __restrict__ eid) {
    int e = blockIdx.x * blockDim.x + threadIdx.x;
    if (e < E) {
        int d = dst[e];
        int p = atomicAdd(&cursor[d], 1);
        ssrc[p] = src[e];
        eid[p] = e;
    }
}

// per-node et mean via CSR (no atomics); 2 nodes per 64-thr block
__global__ __launch_bounds__(64) void etgather_kernel(const float* __restrict__ et,
                                                      const int* __restrict__ rs,
                                                      const int* __restrict__ eid,
                                                      u16* __restrict__ etmean, int n) {
    int node = blockIdx.x * 2 + (threadIdx.x >> 5);
    int c = threadIdx.x & 31;
    if (node >= n) return;
    int s0 = rs[node], s1 = rs[node + 1];
    float a = 0.f;
    for (int e = s0; e < s1; ++e) a += et[(size_t)eid[e] * EDIM + c];
    int cn = s1 - s0;
    float ic = 1.0f / (float)(cn > 1 ? cn : 1);
    etmean[(size_t)node * EDIM + c] = f2bf(a * ic);
}

// ---------------- bf16 prep ----------------
__global__ void conv_h_kernel(const float* __restrict__ h, u16* __restrict__ hb, int total4) {
    int i = blockIdx.x * blockDim.x + threadIdx.x;
    int stride = gridDim.x * blockDim.x;
    for (; i < total4; i += stride) {
        float4 v = reinterpret_cast<const float4*>(h)[i];
        u16x4 o;
        o.x = f2bf(v.x); o.y = f2bf(v.y); o.z = f2bf(v.z); o.w = f2bf(v.w);
        reinterpret_cast<u16x4*>(hb)[i] = o;
    }
}

// WT[mat][c][k] = (k<512 ? W[k][c] : Wem[k-512][c]) as bf16
__global__ void wt_build_kernel(const float* W0, const float* W1, const float* W2,
                                const float* W3, const float* EmA, const float* EmB,
                                u16* __restrict__ WT) {
    int k = blockIdx.x;
    int mat = blockIdx.y;
    int c = threadIdx.x;
    const float* W = (mat == 0) ? W0 : (mat == 1) ? W1 : (mat == 2) ? W2 : W3;
    const float* Em = (mat & 1) ? EmB : EmA;
    float v = (k < 512) ? W[(size_t)k * DDIM + c] : Em[(size_t)(k - 512) * DDIM + c];
    WT[((size_t)mat * DDIM + c) * XK + k] = f2bf(v);
}

// X row = [bf16(self) | bf16(mean agg) | bf16 etmean], one wave per node
__global__ __launch_bounds__(64) void build_x_kernel(
    const u16* __restrict__ hbself, const u16* __restrict__ hbsrc,
    const int* __restrict__ rs, const int* __restrict__ ssrc,
    const u16* __restrict__ etmean, u16* __restrict__ XB) {
    int node = blockIdx.x;
    int t = threadIdx.x;
    int s0 = rs[node], s1 = rs[node + 1];
    int c = s1 - s0;
    float ic = 1.0f / (float)(c > 1 ? c : 1);
    float a0 = 0.f, a1 = 0.f, a2 = 0.f, a3 = 0.f;
    for (int e = s0; e < s1; ++e) {
        int s = ssrc[e];
        u16x4 v = *reinterpret_cast<const u16x4*>(&hbsrc[(size_t)s * DDIM + t * 4]);
        a0 += bf2f(v.x); a1 += bf2f(v.y); a2 += bf2f(v.z); a3 += bf2f(v.w);
    }
    u16* xr = XB + (size_t)node * XK;
    *reinterpret_cast<u16x4*>(&xr[t * 4]) =
        *reinterpret_cast<const u16x4*>(&hbself[(size_t)node * DDIM + t * 4]);
    u16x4 o;
    o.x = f2bf(a0 * ic); o.y = f2bf(a1 * ic); o.z = f2bf(a2 * ic); o.w = f2bf(a3 * ic);
    *reinterpret_cast<u16x4*>(&xr[DDIM + t * 4]) = o;
    if (t < 8)
        reinterpret_cast<u16x4*>(&xr[512])[t] =
            reinterpret_cast<const u16x4*>(&etmean[(size_t)node * EDIM])[t];
}

// ---------------- MFMA GEMM + bias + LayerNorm (+ optional bf16 copy) ----------------
__global__ __launch_bounds__(512) void gemm_ln_kernel(
    const u16* __restrict__ XB, const u16* __restrict__ WT,
    const float* __restrict__ bvec, const float* __restrict__ bem,
    const int* __restrict__ rs,
    const float* __restrict__ g, const float* __restrict__ beta,
    float* __restrict__ out, u16* __restrict__ outbf, int n) {
    __shared__ u16 Al[2 * BM * KC];          // 16 KB
    __shared__ u16 Bl[2 * DDIM * KC];        // 32 KB
    __shared__ float2 mom[BM][4];
    __shared__ float indls[BM];

    const int t = threadIdx.x;
    const int wid = t >> 6, lane = t & 63, lo = lane & 15, hi = lane >> 4;
    const int wr = wid >> 2, wc = wid & 3;
    const int n0 = blockIdx.x * BM;

    if (t < BM) {
        int r = n0 + t;
        indls[t] = (r < n && (rs[r + 1] - rs[r]) > 0) ? 1.0f : 0.0f;
    }

    const int arow = t >> 2;
    const int aslot = (t & 3) ^ ((arow >> 1) & 3);
    const u16* agp = XB + (size_t)(n0 + arow) * XK + aslot * 8;
    const int br0 = t >> 2;
    const int bs0 = (t & 3) ^ ((br0 >> 1) & 3);
    const u16* bgp0 = WT + (size_t)br0 * XK + bs0 * 8;
    const int br1 = 128 + (t >> 2);
    const int bs1 = (t & 3) ^ ((br1 >> 1) & 3);
    const u16* bgp1 = WT + (size_t)br1 * XK + bs1 * 8;

    f32x4 acc[4][4];
#pragma unroll
    for (int i = 0; i < 4; ++i)
#pragma unroll
        for (int j = 0; j < 4; ++j) acc[i][j] = {0.f, 0.f, 0.f, 0.f};

    auto STAGE = [&](int buf, int kk) {
        int k0 = kk * KC;
        GLOAD16(agp + k0, &Al[buf * 4096 + wid * 512]);
        GLOAD16(bgp0 + k0, &Bl[buf * 8192 + wid * 512]);
        GLOAD16(bgp1 + k0, &Bl[buf * 8192 + 4096 + wid * 512]);
    };

    STAGE(0, 0);
    __syncthreads();

    for (int ks = 0; ks < KSTEPS; ++ks) {
        int cur = ks & 1;
        if (ks < KSTEPS - 1) STAGE(1 - cur, ks + 1);

        s16x8 af[4], bf[4];
#pragma unroll
        for (int rt = 0; rt < 4; ++rt) {
            int row = wr * 64 + rt * 16 + lo;
            af[rt] = *reinterpret_cast<const s16x8*>(
                &Al[cur * 4096 + row * KC + ((hi ^ ((row >> 1) & 3)) << 3)]);
        }
#pragma unroll
        for (int ct = 0; ct < 4; ++ct) {
            int c = wc * 64 + ct * 16 + lo;
            bf[ct] = *reinterpret_cast<const s16x8*>(
                &Bl[cur * 8192 + c * KC + ((hi ^ ((c >> 1) & 3)) << 3)]);
        }
#pragma unroll
        for (int rt = 0; rt < 4; ++rt)
#pragma unroll
            for (int ct = 0; ct < 4; ++ct)
                acc[rt][ct] = __builtin_amdgcn_mfma_f32_16x16x32_bf16(
                    af[rt], bf[ct], acc[rt][ct], 0, 0, 0);

        __syncthreads();
    }

    float bb[4], bbem[4], gv[4], bev[4];
#pragma unroll
    for (int ct = 0; ct < 4; ++ct) {
        int c = wc * 64 + ct * 16 + lo;
        bb[ct] = bvec[c]; bbem[ct] = bem[c]; gv[ct] = g[c]; bev[ct] = beta[c];
    }
#pragma unroll
    for (int rt = 0; rt < 4; ++rt)
#pragma unroll
        for (int reg = 0; reg < 4; ++reg) {
            float indv = indls[wr * 64 + rt * 16 + hi * 4 + reg];
#pragma unroll
            for (int ct = 0; ct < 4; ++ct)
                acc[rt][ct][reg] += bb[ct] + indv * bbem[ct];
        }

#pragma unroll
    for (int rt = 0; rt < 4; ++rt)
#pragma unroll
        for (int reg = 0; reg < 4; ++reg) {
            float s = acc[rt][0][reg] + acc[rt][1][reg] + acc[rt][2][reg] + acc[rt][3][reg];
            float q = acc[rt][0][reg] * acc[rt][0][reg] + acc[rt][1][reg] * acc[rt][1][reg]
                    + acc[rt][2][reg] * acc[rt][2][reg] + acc[rt][3][reg] * acc[rt][3][reg];
#pragma unroll
            for (int m = 1; m < 16; m <<= 1) {
                s += __shfl_xor(s, m);
                q += __shfl_xor(q, m);
            }
            if (lo == 0) mom[wr * 64 + rt * 16 + hi * 4 + reg][wc] = make_float2(s, q);
        }
    __syncthreads();

#pragma unroll
    for (int rt = 0; rt < 4; ++rt)
#pragma unroll
        for (int reg = 0; reg < 4; ++reg) {
            int rl = wr * 64 + rt * 16 + hi * 4 + reg;
            float2 m0 = mom[rl][0], m1 = mom[rl][1], m2 = mom[rl][2], m3 = mom[rl][3];
            float s = m0.x + m1.x + m2.x + m3.x;
            float q = m0.y + m1.y + m2.y + m3.y;
            float mean = s * (1.0f / 256.0f);
            float var = q * (1.0f / 256.0f) - mean * mean;
            float inv = rsqrtf(var + 1e-5f);
            int r = n0 + rl;
            if (r < n) {
#pragma unroll
                for (int ct = 0; ct < 4; ++ct) {
                    float val = (acc[rt][ct][reg] - mean) * inv * gv[ct] + bev[ct];
                    size_t o = (size_t)r * DDIM + wc * 64 + ct * 16 + lo;
                    out[o] = val;
                    if (outbf) outbf[o] = f2bf(val);
                }
            }
        }
}

static inline size_t alignup(size_t x) { return (x + 1023) & ~(size_t)1023; }

extern "C" void kernel_launch(void* const* d_in, const int* in_sizes, int n_in,
                              void* d_out, int out_size, void* d_ws, size_t ws_size,
                              hipStream_t stream) {
    const float* h_user  = (const float*)d_in[0];
    const float* h_item  = (const float*)d_in[1];
    const float* et_ub   = (const float*)d_in[2];
    const float* et_bu   = (const float*)d_in[3];
    const float* W0_ub   = (const float*)d_in[4];
    const float* b0_ub   = (const float*)d_in[5];
    const float* W0_bu   = (const float*)d_in[6];
    const float* b0_bu   = (const float*)d_in[7];
    const float* W1_ub   = (const float*)d_in[8];
    const float* b1_ub   = (const float*)d_in[9];
    const float* W1_bu   = (const float*)d_in[10];
    const float* b1_bu   = (const float*)d_in[11];
    const float* bem_ub  = (const float*)d_in[13];
    const float* bem_bu  = (const float*)d_in[15];
    const float* g_u     = (const float*)d_in[16];
    const float* beta_u  = (const float*)d_in[17];
    const float* g_i     = (const float*)d_in[18];
    const float* beta_i  = (const float*)d_in[19];
    const int*   ei_ub   = (const int*)d_in[20];
    const int*   ei_bu   = (const int*)d_in[21];

    const int E = in_sizes[20] / 2;        // 500000
    const int n = in_sizes[0] / DDIM;      // 50000
    const int nPad = ((n + BM - 1) / BM) * BM;
    const int nb = (n + SCHUNK - 1) / SCHUNK;   // 49

    char* w = (char*)d_ws;
    size_t off = 0;
    auto take = [&](size_t bytes) -> void* {
        void* p = w + off;
        off = alignup(off + bytes);
        return p;
    };
    int*   cnt_ub   = (int*)take((size_t)n * 4);
    int*   cnt_bu   = (int*)take((size_t)n * 4);
    size_t zero_bytes = off;                     // only counts need zeroing
    int*   rs_ub    = (int*)take((size_t)(n + 1) * 4);
    int*   rs_bu    = (int*)take((size_t)(n + 1) * 4);
    int*   cur_ub   = (int*)take((size_t)n * 4);
    int*   cur_bu   = (int*)take((size_t)n * 4);
    int*   bsum     = (int*)take((size_t)2 * 64 * 4);
    int*   ssrc_ub  = (int*)take((size_t)E * 4);
    int*   ssrc_bu  = (int*)take((size_t)E * 4);
    int*   eid_ub   = (int*)take((size_t)E * 4);
    int*   eid_bu   = (int*)take((size_t)E * 4);
    u16*   hbu      = (u16*)take((size_t)n * DDIM * 2);
    u16*   hbi      = (u16*)take((size_t)n * DDIM * 2);
    u16*   etm_ub   = (u16*)take((size_t)n * EDIM * 2);
    u16*   etm_bu   = (u16*)take((size_t)n * EDIM * 2);
    u16*   XB       = (u16*)take((size_t)nPad * XK * 2);
    u16*   WT       = (u16*)take((size_t)4 * DDIM * XK * 2);
    (void)ws_size; (void)n_in; (void)out_size;

    const int* src_ub = ei_ub;
    const int* dst_ub = ei_ub + E;
    const int* src_bu = ei_bu;
    const int* dst_bu = ei_bu + E;

    hipMemsetAsync(w, 0, zero_bytes, stream);

    int eb = (E + 255) / 256;
    count_kernel<<<eb, 256, 0, stream>>>(dst_ub, E, cnt_ub);
    count_kernel<<<eb, 256, 0, stream>>>(dst_bu, E, cnt_bu);
    dim3 sg(nb, 2);
    scan_partial_kernel<<<sg, 256, 0, stream>>>(cnt_ub, cnt_bu, n, bsum, nb);
    scan_bsum_kernel<<<1, 128, 0, stream>>>(bsum, nb, rs_ub, rs_bu, n);
    scan_final_kernel<<<sg, 256, 0, stream>>>(cnt_ub, cnt_bu, n, bsum, nb,
                                              rs_ub, cur_ub, rs_bu, cur_bu);
    fill_kernel<<<eb, 256, 0, stream>>>(src_ub, dst_ub, E, cur_ub, ssrc_ub, eid_ub);
    fill_kernel<<<eb, 256, 0, stream>>>(src_bu, dst_bu, E, cur_bu, ssrc_bu, eid_bu);
    etgather_kernel<<<(n + 1) / 2, 64, 0, stream>>>(et_ub, rs_ub, eid_ub, etm_ub, n);
    etgather_kernel<<<(n + 1) / 2, 64, 0, stream>>>(et_bu, rs_bu, eid_bu, etm_bu, n);

    dim3 wtg(XK, 4);
    wt_build_kernel<<<wtg, 256, 0, stream>>>(W0_ub, W0_bu, W1_ub, W1_bu,
                                             (const float*)d_in[12], (const float*)d_in[14], WT);

    float* hu_out = (float*)d_out;
    float* hi_out = (float*)d_out + (size_t)n * DDIM;
    int total4 = n * DDIM / 4;
    int cvb = 2048;
    int gb = (n + BM - 1) / BM;
    const u16* WT0 = WT;
    const u16* WT1 = WT + (size_t)DDIM * XK;
    const u16* WT2 = WT + (size_t)2 * DDIM * XK;
    const u16* WT3 = WT + (size_t)3 * DDIM * XK;

    // ---- layer 0 ----
    conv_h_kernel<<<cvb, 256, 0, stream>>>(h_user, hbu, total4);
    conv_h_kernel<<<cvb, 256, 0, stream>>>(h_item, hbi, total4);
    // item update: reads hbi(self)+hbu(src). NO outbf: hbi still needed below.
    build_x_kernel<<<n, 64, 0, stream>>>(hbi, hbu, rs_ub, ssrc_ub, etm_ub, XB);
    gemm_ln_kernel<<<gb, 512, 0, stream>>>(XB, WT0, b0_ub, bem_ub, rs_ub,
                                           g_i, beta_i, hi_out, nullptr, n);
    // user update: consumes original hbi here; after this, hbu is dead ->
    // gemm may fuse its bf16 output into hbu.
    build_x_kernel<<<n, 64, 0, stream>>>(hbu, hbi, rs_bu, ssrc_bu, etm_bu, XB);
    gemm_ln_kernel<<<gb, 512, 0, stream>>>(XB, WT1, b0_bu, bem_bu, rs_bu,
                                           g_u, beta_u, hu_out, hbu, n);
    // now hbi (original h_item) is dead; snapshot layer-0 item output into it.
    conv_h_kernel<<<cvb, 256, 0, stream>>>(hi_out, hbi, total4);

    // ---- layer 1 ---- (hbi/hbu are layer-0 outputs, never modified below)
    build_x_kernel<<<n, 64, 0, stream>>>(hbi, hbu, rs_ub, ssrc_ub, etm_ub, XB);
    gemm_ln_kernel<<<gb, 512, 0, stream>>>(XB, WT2, b1_ub, bem_ub, rs_ub,
                                           g_i, beta_i, hi_out, nullptr, n);
    build_x_kernel<<<n, 64, 0, stream>>>(hbu, hbi, rs_bu, ssrc_bu, etm_bu, XB);
    gemm_ln_kernel<<<gb, 512, 0, stream>>>(XB, WT3, b1_bu, bem_bu, rs_bu,
                                           g_u, beta_u, hu_out, nullptr, n);
}

// Round 5
// 647.824 us; speedup vs baseline: 4.3445x; 1.0650x over previous
//
#include <hip/hip_runtime.h>

// HetSAGE: 2-layer heterogeneous GraphSAGE, N=50000/type, E=500000/type, D=256.
// R4: 4-deep load batching in CSR gather kernels (etgather, build_x) to break
// the serial load-latency chain; layer-0 GEMMs emit bf16 only (dead f32
// writes and the post-L0 conv_h removed; separate hbi1/hbu1 kill aliasing).

#define DDIM 256
#define EDIM 32
#define XK 544          // 512 + 32
#define BM 128          // GEMM row tile
#define KC 32           // K chunk
#define KSTEPS 17       // 544/32
#define SCHUNK 1024     // scan elements per block

typedef unsigned short u16;
typedef short s16x8 __attribute__((ext_vector_type(8)));
typedef float f32x4 __attribute__((ext_vector_type(4)));
typedef u16 u16x4 __attribute__((ext_vector_type(4)));

__device__ __forceinline__ u16 f2bf(float f) {
    unsigned u = __builtin_bit_cast(unsigned, f);
    u += 0x7FFF + ((u >> 16) & 1);           // RNE
    return (u16)(u >> 16);
}
__device__ __forceinline__ float bf2f(u16 u) {
    unsigned x = ((unsigned)u) << 16;
    return __builtin_bit_cast(float, x);
}

#define GLOAD16(gp, lp)                                                        \
    __builtin_amdgcn_global_load_lds(                                          \
        (const __attribute__((address_space(1))) unsigned int*)(gp),           \
        (__attribute__((address_space(3))) unsigned int*)(lp), 16, 0, 0)

// ---------------- CSR build ----------------
__global__ void count_kernel(const int* __restrict__ dst, int E, int* __restrict__ cnt) {
    int e = blockIdx.x * blockDim.x + threadIdx.x;
    if (e < E) atomicAdd(&cnt[dst[e]], 1);
}

__global__ void scan_partial_kernel(const int* __restrict__ cnt0, const int* __restrict__ cnt1,
                                    int n, int* __restrict__ bsum, int nb) {
    const int* cnt = blockIdx.y ? cnt1 : cnt0;
    int base = blockIdx.x * SCHUNK + threadIdx.x * 4;
    int s = 0;
#pragma unroll
    for (int i = 0; i < 4; ++i) {
        int idx = base + i;
        if (idx < n) s += cnt[idx];
    }
#pragma unroll
    for (int m = 1; m < 64; m <<= 1) s += __shfl_xor(s, m);
    __shared__ int ws[4];
    int lane = threadIdx.x & 63, wid = threadIdx.x >> 6;
    if (lane == 0) ws[wid] = s;
    __syncthreads();
    if (threadIdx.x == 0) bsum[blockIdx.y * nb + blockIdx.x] = ws[0] + ws[1] + ws[2] + ws[3];
}

__global__ void scan_bsum_kernel(int* __restrict__ bsum, int nb,
                                 int* __restrict__ rs0, int* __restrict__ rs1, int n) {
    int wid = threadIdx.x >> 6, lane = threadIdx.x & 63;
    int* bs = bsum + wid * nb;
    int v = (lane < nb) ? bs[lane] : 0;
    int ps = v;
#pragma unroll
    for (int m = 1; m < 64; m <<= 1) {
        int u = __shfl_up(ps, m);
        if (lane >= m) ps += u;
    }
    if (lane < nb) bs[lane] = ps - v;   // exclusive
    if (lane == nb - 1) (wid ? rs1 : rs0)[n] = ps;
}

__global__ void scan_final_kernel(const int* __restrict__ cnt0, const int* __restrict__ cnt1,
                                  int n, const int* __restrict__ bsum, int nb,
                                  int* __restrict__ rs0, int* __restrict__ cur0,
                                  int* __restrict__ rs1, int* __restrict__ cur1) {
    const int* cnt = blockIdx.y ? cnt1 : cnt0;
    int* rs  = blockIdx.y ? rs1 : rs0;
    int* cur = blockIdx.y ? cur1 : cur0;
    int t = threadIdx.x;
    int base = blockIdx.x * SCHUNK + t * 4;
    int v[4];
    int s = 0;
#pragma unroll
    for (int i = 0; i < 4; ++i) {
        int idx = base + i;
        v[i] = (idx < n) ? cnt[idx] : 0;
        s += v[i];
    }
    int lane = t & 63, wid = t >> 6;
    int ps = s;
#pragma unroll
    for (int m = 1; m < 64; m <<= 1) {
        int u = __shfl_up(ps, m);
        if (lane >= m) ps += u;
    }
    __shared__ int wsum[4];
    if (lane == 63) wsum[wid] = ps;
    __syncthreads();
    int wofs = 0;
    for (int i = 0; i < wid; ++i) wofs += wsum[i];
    int run = bsum[blockIdx.y * nb + blockIdx.x] + wofs + ps - s;
#pragma unroll
    for (int i = 0; i < 4; ++i) {
        int idx = base + i;
        if (idx < n) {
            rs[idx] = run;
            cur[idx] = run;
            run += v[i];
        }
    }
}

__global__ void fill_kernel(const int* __restrict__ src, const int* __restrict__ dst, int E,
                            int* __restrict__ cursor, int* __restrict__ ssrc,
                            int* __restrict__ eid) {
    int e = blockIdx.x * blockDim.x + threadIdx.x;
    if (e < E) {
        int d = dst[e];
        int p = atomicAdd(&cursor[d], 1);
        ssrc[p] = src[e];
        eid[p] = e;
    }
}

// per-node et mean via CSR; 1 node/wave, 4 waves/block; 2-edge lane-parallel
// x 4-deep load batching = 8 rows in flight.
__global__ __launch_bounds__(256) void etgather_kernel(const float* __restrict__ et,
                                                       const int* __restrict__ rs,
                                                       const int* __restrict__ eid,
                                                       u16* __restrict__ etmean, int n) {
    int node = blockIdx.x * 4 + (threadIdx.x >> 6);
    if (node >= n) return;
    int lane = threadIdx.x & 63;
    int c = lane & 31, eh = lane >> 5;
    int s0 = rs[node], s1 = rs[node + 1];
    float a = 0.f;
    for (int base = s0 + eh; base < s1; base += 8) {
        int idx[4];
#pragma unroll
        for (int j = 0; j < 4; ++j) {
            int e = base + 2 * j;
            idx[j] = eid[e < s1 ? e : s0];     // clamped: always a valid slot
        }
        float v[4];
#pragma unroll
        for (int j = 0; j < 4; ++j)
            v[j] = et[(size_t)idx[j] * EDIM + c];  // 4 loads in flight
#pragma unroll
        for (int j = 0; j < 4; ++j)
            if (base + 2 * j < s1) a += v[j];
    }
    a += __shfl_xor(a, 32);
    if (eh == 0) {
        int cn = s1 - s0;
        float ic = 1.0f / (float)(cn > 1 ? cn : 1);
        etmean[(size_t)node * EDIM + c] = f2bf(a * ic);
    }
}

// ---------------- bf16 prep ----------------
__global__ void conv_h_kernel(const float* __restrict__ h, u16* __restrict__ hb, int total4) {
    int i = blockIdx.x * blockDim.x + threadIdx.x;
    int stride = gridDim.x * blockDim.x;
    for (; i < total4; i += stride) {
        float4 v = reinterpret_cast<const float4*>(h)[i];
        u16x4 o;
        o.x = f2bf(v.x); o.y = f2bf(v.y); o.z = f2bf(v.z); o.w = f2bf(v.w);
        reinterpret_cast<u16x4*>(hb)[i] = o;
    }
}

// WT[mat][c][k] = (k<512 ? W[k][c] : Wem[k-512][c]) as bf16
__global__ void wt_build_kernel(const float* W0, const float* W1, const float* W2,
                                const float* W3, const float* EmA, const float* EmB,
                                u16* __restrict__ WT) {
    int k = blockIdx.x;
    int mat = blockIdx.y;
    int c = threadIdx.x;
    const float* W = (mat == 0) ? W0 : (mat == 1) ? W1 : (mat == 2) ? W2 : W3;
    const float* Em = (mat & 1) ? EmB : EmA;
    float v = (k < 512) ? W[(size_t)k * DDIM + c] : Em[(size_t)(k - 512) * DDIM + c];
    WT[((size_t)mat * DDIM + c) * XK + k] = f2bf(v);
}

// X row = [bf16(self) | bf16(mean agg) | bf16 etmean]; 1 node/wave, 4/block;
// 4-deep row-load batching.
__global__ __launch_bounds__(256) void build_x_kernel(
    const u16* __restrict__ hbself, const u16* __restrict__ hbsrc,
    const int* __restrict__ rs, const int* __restrict__ ssrc,
    const u16* __restrict__ etmean, u16* __restrict__ XB, int n) {
    int node = blockIdx.x * 4 + (threadIdx.x >> 6);
    if (node >= n) return;
    int t = threadIdx.x & 63;
    int s0 = rs[node], s1 = rs[node + 1];
    int cdeg = s1 - s0;
    float ic = 1.0f / (float)(cdeg > 1 ? cdeg : 1);
    float a0 = 0.f, a1 = 0.f, a2 = 0.f, a3 = 0.f;
    for (int base = s0; base < s1; base += 4) {
        int si[4];
#pragma unroll
        for (int j = 0; j < 4; ++j) {
            int e = base + j;
            si[j] = ssrc[e < s1 ? e : s0];     // clamped valid slot
        }
        u16x4 v[4];
#pragma unroll
        for (int j = 0; j < 4; ++j)
            v[j] = *reinterpret_cast<const u16x4*>(&hbsrc[(size_t)si[j] * DDIM + t * 4]);
#pragma unroll
        for (int j = 0; j < 4; ++j)
            if (base + j < s1) {
                a0 += bf2f(v[j].x); a1 += bf2f(v[j].y);
                a2 += bf2f(v[j].z); a3 += bf2f(v[j].w);
            }
    }
    u16* xr = XB + (size_t)node * XK;
    *reinterpret_cast<u16x4*>(&xr[t * 4]) =
        *reinterpret_cast<const u16x4*>(&hbself[(size_t)node * DDIM + t * 4]);
    u16x4 o;
    o.x = f2bf(a0 * ic); o.y = f2bf(a1 * ic); o.z = f2bf(a2 * ic); o.w = f2bf(a3 * ic);
    *reinterpret_cast<u16x4*>(&xr[DDIM + t * 4]) = o;
    if (t < 8)
        reinterpret_cast<u16x4*>(&xr[512])[t] =
            reinterpret_cast<const u16x4*>(&etmean[(size_t)node * EDIM])[t];
}

// ---------------- MFMA GEMM + bias + LayerNorm ----------------
// out (f32) and outbf (bf16) both optional.
__global__ __launch_bounds__(512) void gemm_ln_kernel(
    const u16* __restrict__ XB, const u16* __restrict__ WT,
    const float* __restrict__ bvec, const float* __restrict__ bem,
    const int* __restrict__ rs,
    const float* __restrict__ g, const float* __restrict__ beta,
    float* __restrict__ out, u16* __restrict__ outbf, int n) {
    __shared__ u16 Al[2 * BM * KC];          // 16 KB
    __shared__ u16 Bl[2 * DDIM * KC];        // 32 KB
    __shared__ float2 mom[BM][4];
    __shared__ float indls[BM];

    const int t = threadIdx.x;
    const int wid = t >> 6, lane = t & 63, lo = lane & 15, hi = lane >> 4;
    const int wr = wid >> 2, wc = wid & 3;
    const int n0 = blockIdx.x * BM;

    if (t < BM) {
        int r = n0 + t;
        indls[t] = (r < n && (rs[r + 1] - rs[r]) > 0) ? 1.0f : 0.0f;
    }

    const int arow = t >> 2;
    const int aslot = (t & 3) ^ ((arow >> 1) & 3);
    const u16* agp = XB + (size_t)(n0 + arow) * XK + aslot * 8;
    const int br0 = t >> 2;
    const int bs0 = (t & 3) ^ ((br0 >> 1) & 3);
    const u16* bgp0 = WT + (size_t)br0 * XK + bs0 * 8;
    const int br1 = 128 + (t >> 2);
    const int bs1 = (t & 3) ^ ((br1 >> 1) & 3);
    const u16* bgp1 = WT + (size_t)br1 * XK + bs1 * 8;

    f32x4 acc[4][4];
#pragma unroll
    for (int i = 0; i < 4; ++i)
#pragma unroll
        for (int j = 0; j < 4; ++j) acc[i][j] = {0.f, 0.f, 0.f, 0.f};

    auto STAGE = [&](int buf, int kk) {
        int k0 = kk * KC;
        GLOAD16(agp + k0, &Al[buf * 4096 + wid * 512]);
        GLOAD16(bgp0 + k0, &Bl[buf * 8192 + wid * 512]);
        GLOAD16(bgp1 + k0, &Bl[buf * 8192 + 4096 + wid * 512]);
    };

    STAGE(0, 0);
    __syncthreads();

    for (int ks = 0; ks < KSTEPS; ++ks) {
        int cur = ks & 1;
        if (ks < KSTEPS - 1) STAGE(1 - cur, ks + 1);

        s16x8 af[4], bf[4];
#pragma unroll
        for (int rt = 0; rt < 4; ++rt) {
            int row = wr * 64 + rt * 16 + lo;
            af[rt] = *reinterpret_cast<const s16x8*>(
                &Al[cur * 4096 + row * KC + ((hi ^ ((row >> 1) & 3)) << 3)]);
        }
#pragma unroll
        for (int ct = 0; ct < 4; ++ct) {
            int c = wc * 64 + ct * 16 + lo;
            bf[ct] = *reinterpret_cast<const s16x8*>(
                &Bl[cur * 8192 + c * KC + ((hi ^ ((c >> 1) & 3)) << 3)]);
        }
#pragma unroll
        for (int rt = 0; rt < 4; ++rt)
#pragma unroll
            for (int ct = 0; ct < 4; ++ct)
                acc[rt][ct] = __builtin_amdgcn_mfma_f32_16x16x32_bf16(
                    af[rt], bf[ct], acc[rt][ct], 0, 0, 0);

        __syncthreads();
    }

    float bb[4], bbem[4], gv[4], bev[4];
#pragma unroll
    for (int ct = 0; ct < 4; ++ct) {
        int c = wc * 64 + ct * 16 + lo;
        bb[ct] = bvec[c]; bbem[ct] = bem[c]; gv[ct] = g[c]; bev[ct] = beta[c];
    }
#pragma unroll
    for (int rt = 0; rt < 4; ++rt)
#pragma unroll
        for (int reg = 0; reg < 4; ++reg) {
            float indv = indls[wr * 64 + rt * 16 + hi * 4 + reg];
#pragma unroll
            for (int ct = 0; ct < 4; ++ct)
                acc[rt][ct][reg] += bb[ct] + indv * bbem[ct];
        }

#pragma unroll
    for (int rt = 0; rt < 4; ++rt)
#pragma unroll
        for (int reg = 0; reg < 4; ++reg) {
            float s = acc[rt][0][reg] + acc[rt][1][reg] + acc[rt][2][reg] + acc[rt][3][reg];
            float q = acc[rt][0][reg] * acc[rt][0][reg] + acc[rt][1][reg] * acc[rt][1][reg]
                    + acc[rt][2][reg] * acc[rt][2][reg] + acc[rt][3][reg] * acc[rt][3][reg];
#pragma unroll
            for (int m = 1; m < 16; m <<= 1) {
                s += __shfl_xor(s, m);
                q += __shfl_xor(q, m);
            }
            if (lo == 0) mom[wr * 64 + rt * 16 + hi * 4 + reg][wc] = make_float2(s, q);
        }
    __syncthreads();

#pragma unroll
    for (int rt = 0; rt < 4; ++rt)
#pragma unroll
        for (int reg = 0; reg < 4; ++reg) {
            int rl = wr * 64 + rt * 16 + hi * 4 + reg;
            float2 m0 = mom[rl][0], m1 = mom[rl][1], m2 = mom[rl][2], m3 = mom[rl][3];
            float s = m0.x + m1.x + m2.x + m3.x;
            float q = m0.y + m1.y + m2.y + m3.y;
            float mean = s * (1.0f / 256.0f);
            float var = q * (1.0f / 256.0f) - mean * mean;
            float inv = rsqrtf(var + 1e-5f);
            int r = n0 + rl;
            if (r < n) {
#pragma unroll
                for (int ct = 0; ct < 4; ++ct) {
                    float val = (acc[rt][ct][reg] - mean) * inv * gv[ct] + bev[ct];
                    size_t o = (size_t)r * DDIM + wc * 64 + ct * 16 + lo;
                    if (out) out[o] = val;
                    if (outbf) outbf[o] = f2bf(val);
                }
            }
        }
}

static inline size_t alignup(size_t x) { return (x + 1023) & ~(size_t)1023; }

extern "C" void kernel_launch(void* const* d_in, const int* in_sizes, int n_in,
                              void* d_out, int out_size, void* d_ws, size_t ws_size,
                              hipStream_t stream) {
    const float* h_user  = (const float*)d_in[0];
    const float* h_item  = (const float*)d_in[1];
    const float* et_ub   = (const float*)d_in[2];
    const float* et_bu   = (const float*)d_in[3];
    const float* W0_ub   = (const float*)d_in[4];
    const float* b0_ub   = (const float*)d_in[5];
    const float* W0_bu   = (const float*)d_in[6];
    const float* b0_bu   = (const float*)d_in[7];
    const float* W1_ub   = (const float*)d_in[8];
    const float* b1_ub   = (const float*)d_in[9];
    const float* W1_bu   = (const float*)d_in[10];
    const float* b1_bu   = (const float*)d_in[11];
    const float* bem_ub  = (const float*)d_in[13];
    const float* bem_bu  = (const float*)d_in[15];
    const float* g_u     = (const float*)d_in[16];
    const float* beta_u  = (const float*)d_in[17];
    const float* g_i     = (const float*)d_in[18];
    const float* beta_i  = (const float*)d_in[19];
    const int*   ei_ub   = (const int*)d_in[20];
    const int*   ei_bu   = (const int*)d_in[21];

    const int E = in_sizes[20] / 2;        // 500000
    const int n = in_sizes[0] / DDIM;      // 50000
    const int nPad = ((n + BM - 1) / BM) * BM;
    const int nb = (n + SCHUNK - 1) / SCHUNK;   // 49

    char* w = (char*)d_ws;
    size_t off = 0;
    auto take = [&](size_t bytes) -> void* {
        void* p = w + off;
        off = alignup(off + bytes);
        return p;
    };
    int*   cnt_ub   = (int*)take((size_t)n * 4);
    int*   cnt_bu   = (int*)take((size_t)n * 4);
    size_t zero_bytes = off;                     // only counts need zeroing
    int*   rs_ub    = (int*)take((size_t)(n + 1) * 4);
    int*   rs_bu    = (int*)take((size_t)(n + 1) * 4);
    int*   cur_ub   = (int*)take((size_t)n * 4);
    int*   cur_bu   = (int*)take((size_t)n * 4);
    int*   bsum     = (int*)take((size_t)2 * 64 * 4);
    int*   ssrc_ub  = (int*)take((size_t)E * 4);
    int*   ssrc_bu  = (int*)take((size_t)E * 4);
    int*   eid_ub   = (int*)take((size_t)E * 4);
    int*   eid_bu   = (int*)take((size_t)E * 4);
    u16*   hbu0     = (u16*)take((size_t)n * DDIM * 2);
    u16*   hbi0     = (u16*)take((size_t)n * DDIM * 2);
    u16*   hbu1     = (u16*)take((size_t)n * DDIM * 2);
    u16*   hbi1     = (u16*)take((size_t)n * DDIM * 2);
    u16*   etm_ub   = (u16*)take((size_t)n * EDIM * 2);
    u16*   etm_bu   = (u16*)take((size_t)n * EDIM * 2);
    u16*   XB       = (u16*)take((size_t)nPad * XK * 2);
    u16*   WT       = (u16*)take((size_t)4 * DDIM * XK * 2);
    (void)ws_size; (void)n_in; (void)out_size;

    const int* src_ub = ei_ub;
    const int* dst_ub = ei_ub + E;
    const int* src_bu = ei_bu;
    const int* dst_bu = ei_bu + E;

    hipMemsetAsync(w, 0, zero_bytes, stream);

    int eb = (E + 255) / 256;
    count_kernel<<<eb, 256, 0, stream>>>(dst_ub, E, cnt_ub);
    count_kernel<<<eb, 256, 0, stream>>>(dst_bu, E, cnt_bu);
    dim3 sg(nb, 2);
    scan_partial_kernel<<<sg, 256, 0, stream>>>(cnt_ub, cnt_bu, n, bsum, nb);
    scan_bsum_kernel<<<1, 128, 0, stream>>>(bsum, nb, rs_ub, rs_bu, n);
    scan_final_kernel<<<sg, 256, 0, stream>>>(cnt_ub, cnt_bu, n, bsum, nb,
                                              rs_ub, cur_ub, rs_bu, cur_bu);
    fill_kernel<<<eb, 256, 0, stream>>>(src_ub, dst_ub, E, cur_ub, ssrc_ub, eid_ub);
    fill_kernel<<<eb, 256, 0, stream>>>(src_bu, dst_bu, E, cur_bu, ssrc_bu, eid_bu);
    int ngb = (n + 3) / 4;
    etgather_kernel<<<ngb, 256, 0, stream>>>(et_ub, rs_ub, eid_ub, etm_ub, n);
    etgather_kernel<<<ngb, 256, 0, stream>>>(et_bu, rs_bu, eid_bu, etm_bu, n);

    dim3 wtg(XK, 4);
    wt_build_kernel<<<wtg, 256, 0, stream>>>(W0_ub, W0_bu, W1_ub, W1_bu,
                                             (const float*)d_in[12], (const float*)d_in[14], WT);

    float* hu_out = (float*)d_out;
    float* hi_out = (float*)d_out + (size_t)n * DDIM;
    int total4 = n * DDIM / 4;
    int cvb = 2048;
    int gb = (n + BM - 1) / BM;
    const u16* WT0 = WT;
    const u16* WT1 = WT + (size_t)DDIM * XK;
    const u16* WT2 = WT + (size_t)2 * DDIM * XK;
    const u16* WT3 = WT + (size_t)3 * DDIM * XK;

    // ---- layer 0: bf16-only outputs into fresh buffers (no aliasing) ----
    conv_h_kernel<<<cvb, 256, 0, stream>>>(h_user, hbu0, total4);
    conv_h_kernel<<<cvb, 256, 0, stream>>>(h_item, hbi0, total4);
    build_x_kernel<<<ngb, 256, 0, stream>>>(hbi0, hbu0, rs_ub, ssrc_ub, etm_ub, XB, n);
    gemm_ln_kernel<<<gb, 512, 0, stream>>>(XB, WT0, b0_ub, bem_ub, rs_ub,
                                           g_i, beta_i, nullptr, hbi1, n);
    build_x_kernel<<<ngb, 256, 0, stream>>>(hbu0, hbi0, rs_bu, ssrc_bu, etm_bu, XB, n);
    gemm_ln_kernel<<<gb, 512, 0, stream>>>(XB, WT1, b0_bu, bem_bu, rs_bu,
                                           g_u, beta_u, nullptr, hbu1, n);

    // ---- layer 1: f32 outputs to d_out ----
    build_x_kernel<<<ngb, 256, 0, stream>>>(hbi1, hbu1, rs_ub, ssrc_ub, etm_ub, XB, n);
    gemm_ln_kernel<<<gb, 512, 0, stream>>>(XB, WT2, b1_ub, bem_ub, rs_ub,
                                           g_i, beta_i, hi_out, nullptr, n);
    build_x_kernel<<<ngb, 256, 0, stream>>>(hbu1, hbi1, rs_bu, ssrc_bu, etm_bu, XB, n);
    gemm_ln_kernel<<<gb, 512, 0, stream>>>(XB, WT3, b1_bu, bem_bu, rs_bu,
                                           g_u, beta_u, hu_out, nullptr, n);
}

// Round 6
// 593.060 us; speedup vs baseline: 4.7457x; 1.0923x over previous
//
#include <hip/hip_runtime.h>

// HetSAGE: 2-layer heterogeneous GraphSAGE, N=50000/type, E=500000/type, D=256.
// R5: gemm BM 128->64 (grid 391->782, 3 blocks/CU resident: occupancy was the
// gemm limiter at 16%), and A-panel self-half staged directly from the hb
// table (XB2 = [agg|et] only, stride 288 -> ~51 MB less traffic/layer-half).

#define DDIM 256
#define EDIM 32
#define XK 544          // WT row stride (total K)
#define XA 288          // XB2 row stride: 256 agg + 32 et
#define BM 64           // GEMM row tile
#define KC 32           // K chunk
#define KSTEPS 17       // 544/32
#define SCHUNK 1024     // scan elements per block

typedef unsigned short u16;
typedef short s16x8 __attribute__((ext_vector_type(8)));
typedef float f32x4 __attribute__((ext_vector_type(4)));
typedef u16 u16x4 __attribute__((ext_vector_type(4)));

__device__ __forceinline__ u16 f2bf(float f) {
    unsigned u = __builtin_bit_cast(unsigned, f);
    u += 0x7FFF + ((u >> 16) & 1);           // RNE
    return (u16)(u >> 16);
}
__device__ __forceinline__ float bf2f(u16 u) {
    unsigned x = ((unsigned)u) << 16;
    return __builtin_bit_cast(float, x);
}

#define GLOAD16(gp, lp)                                                        \
    __builtin_amdgcn_global_load_lds(                                          \
        (const __attribute__((address_space(1))) unsigned int*)(gp),           \
        (__attribute__((address_space(3))) unsigned int*)(lp), 16, 0, 0)

// ---------------- CSR build ----------------
__global__ void count_kernel(const int* __restrict__ dst, int E, int* __restrict__ cnt) {
    int e = blockIdx.x * blockDim.x + threadIdx.x;
    if (e < E) atomicAdd(&cnt[dst[e]], 1);
}

__global__ void scan_partial_kernel(const int* __restrict__ cnt0, const int* __restrict__ cnt1,
                                    int n, int* __restrict__ bsum, int nb) {
    const int* cnt = blockIdx.y ? cnt1 : cnt0;
    int base = blockIdx.x * SCHUNK + threadIdx.x * 4;
    int s = 0;
#pragma unroll
    for (int i = 0; i < 4; ++i) {
        int idx = base + i;
        if (idx < n) s += cnt[idx];
    }
#pragma unroll
    for (int m = 1; m < 64; m <<= 1) s += __shfl_xor(s, m);
    __shared__ int ws[4];
    int lane = threadIdx.x & 63, wid = threadIdx.x >> 6;
    if (lane == 0) ws[wid] = s;
    __syncthreads();
    if (threadIdx.x == 0) bsum[blockIdx.y * nb + blockIdx.x] = ws[0] + ws[1] + ws[2] + ws[3];
}

__global__ void scan_bsum_kernel(int* __restrict__ bsum, int nb,
                                 int* __restrict__ rs0, int* __restrict__ rs1, int n) {
    int wid = threadIdx.x >> 6, lane = threadIdx.x & 63;
    int* bs = bsum + wid * nb;
    int v = (lane < nb) ? bs[lane] : 0;
    int ps = v;
#pragma unroll
    for (int m = 1; m < 64; m <<= 1) {
        int u = __shfl_up(ps, m);
        if (lane >= m) ps += u;
    }
    if (lane < nb) bs[lane] = ps - v;   // exclusive
    if (lane == nb - 1) (wid ? rs1 : rs0)[n] = ps;
}

__global__ void scan_final_kernel(const int* __restrict__ cnt0, const int* __restrict__ cnt1,
                                  int n, const int* __restrict__ bsum, int nb,
                                  int* __restrict__ rs0, int* __restrict__ cur0,
                                  int* __restrict__ rs1, int* __restrict__ cur1) {
    const int* cnt = blockIdx.y ? cnt1 : cnt0;
    int* rs  = blockIdx.y ? rs1 : rs0;
    int* cur = blockIdx.y ? cur1 : cur0;
    int t = threadIdx.x;
    int base = blockIdx.x * SCHUNK + t * 4;
    int v[4];
    int s = 0;
#pragma unroll
    for (int i = 0; i < 4; ++i) {
        int idx = base + i;
        v[i] = (idx < n) ? cnt[idx] : 0;
        s += v[i];
    }
    int lane = t & 63, wid = t >> 6;
    int ps = s;
#pragma unroll
    for (int m = 1; m < 64; m <<= 1) {
        int u = __shfl_up(ps, m);
        if (lane >= m) ps += u;
    }
    __shared__ int wsum[4];
    if (lane == 63) wsum[wid] = ps;
    __syncthreads();
    int wofs = 0;
    for (int i = 0; i < wid; ++i) wofs += wsum[i];
    int run = bsum[blockIdx.y * nb + blockIdx.x] + wofs + ps - s;
#pragma unroll
    for (int i = 0; i < 4; ++i) {
        int idx = base + i;
        if (idx < n) {
            rs[idx] = run;
            cur[idx] = run;
            run += v[i];
        }
    }
}

__global__ void fill_kernel(const int* __restrict__ src, const int* __restrict__ dst, int E,
                            int* __restrict__ cursor, int* __restrict__ ssrc,
                            int* __restrict__ eid) {
    int e = blockIdx.x * blockDim.x + threadIdx.x;
    if (e < E) {
        int d = dst[e];
        int p = atomicAdd(&cursor[d], 1);
        ssrc[p] = src[e];
        eid[p] = e;
    }
}

// per-node et mean via CSR; 1 node/wave, 4 waves/block; 2-edge lane-parallel
// x 4-deep load batching = 8 rows in flight.
__global__ __launch_bounds__(256) void etgather_kernel(const float* __restrict__ et,
                                                       const int* __restrict__ rs,
                                                       const int* __restrict__ eid,
                                                       u16* __restrict__ etmean, int n) {
    int node = blockIdx.x * 4 + (threadIdx.x >> 6);
    if (node >= n) return;
    int lane = threadIdx.x & 63;
    int c = lane & 31, eh = lane >> 5;
    int s0 = rs[node], s1 = rs[node + 1];
    float a = 0.f;
    for (int base = s0 + eh; base < s1; base += 8) {
        int idx[4];
#pragma unroll
        for (int j = 0; j < 4; ++j) {
            int e = base + 2 * j;
            idx[j] = eid[e < s1 ? e : s0];     // clamped: always a valid slot
        }
        float v[4];
#pragma unroll
        for (int j = 0; j < 4; ++j)
            v[j] = et[(size_t)idx[j] * EDIM + c];  // 4 loads in flight
#pragma unroll
        for (int j = 0; j < 4; ++j)
            if (base + 2 * j < s1) a += v[j];
    }
    a += __shfl_xor(a, 32);
    if (eh == 0) {
        int cn = s1 - s0;
        float ic = 1.0f / (float)(cn > 1 ? cn : 1);
        etmean[(size_t)node * EDIM + c] = f2bf(a * ic);
    }
}

// ---------------- bf16 prep ----------------
__global__ void conv_h_kernel(const float* __restrict__ h, u16* __restrict__ hb, int total4) {
    int i = blockIdx.x * blockDim.x + threadIdx.x;
    int stride = gridDim.x * blockDim.x;
    for (; i < total4; i += stride) {
        float4 v = reinterpret_cast<const float4*>(h)[i];
        u16x4 o;
        o.x = f2bf(v.x); o.y = f2bf(v.y); o.z = f2bf(v.z); o.w = f2bf(v.w);
        reinterpret_cast<u16x4*>(hb)[i] = o;
    }
}

// WT[mat][c][k] = (k<512 ? W[k][c] : Wem[k-512][c]) as bf16
__global__ void wt_build_kernel(const float* W0, const float* W1, const float* W2,
                                const float* W3, const float* EmA, const float* EmB,
                                u16* __restrict__ WT) {
    int k = blockIdx.x;
    int mat = blockIdx.y;
    int c = threadIdx.x;
    const float* W = (mat == 0) ? W0 : (mat == 1) ? W1 : (mat == 2) ? W2 : W3;
    const float* Em = (mat & 1) ? EmB : EmA;
    float v = (k < 512) ? W[(size_t)k * DDIM + c] : Em[(size_t)(k - 512) * DDIM + c];
    WT[((size_t)mat * DDIM + c) * XK + k] = f2bf(v);
}

// XB2 row = [bf16(mean agg) | bf16 etmean] (no self copy; gemm reads hb
// directly). 1 node/wave, 4/block; 4-deep row-load batching.
__global__ __launch_bounds__(256) void build_x_kernel(
    const u16* __restrict__ hbsrc,
    const int* __restrict__ rs, const int* __restrict__ ssrc,
    const u16* __restrict__ etmean, u16* __restrict__ XB2, int n) {
    int node = blockIdx.x * 4 + (threadIdx.x >> 6);
    if (node >= n) return;
    int t = threadIdx.x & 63;
    int s0 = rs[node], s1 = rs[node + 1];
    int cdeg = s1 - s0;
    float ic = 1.0f / (float)(cdeg > 1 ? cdeg : 1);
    float a0 = 0.f, a1 = 0.f, a2 = 0.f, a3 = 0.f;
    for (int base = s0; base < s1; base += 4) {
        int si[4];
#pragma unroll
        for (int j = 0; j < 4; ++j) {
            int e = base + j;
            si[j] = ssrc[e < s1 ? e : s0];     // clamped valid slot
        }
        u16x4 v[4];
#pragma unroll
        for (int j = 0; j < 4; ++j)
            v[j] = *reinterpret_cast<const u16x4*>(&hbsrc[(size_t)si[j] * DDIM + t * 4]);
#pragma unroll
        for (int j = 0; j < 4; ++j)
            if (base + j < s1) {
                a0 += bf2f(v[j].x); a1 += bf2f(v[j].y);
                a2 += bf2f(v[j].z); a3 += bf2f(v[j].w);
            }
    }
    u16* xr = XB2 + (size_t)node * XA;
    u16x4 o;
    o.x = f2bf(a0 * ic); o.y = f2bf(a1 * ic); o.z = f2bf(a2 * ic); o.w = f2bf(a3 * ic);
    *reinterpret_cast<u16x4*>(&xr[t * 4]) = o;
    if (t < 8)
        reinterpret_cast<u16x4*>(&xr[DDIM])[t] =
            reinterpret_cast<const u16x4*>(&etmean[(size_t)node * EDIM])[t];
}

// ---------------- MFMA GEMM + bias + LayerNorm ----------------
// A panel: K-chunks 0..7 from hbA (self, stride 256), chunks 8..16 from XB2
// ([agg|et], stride 288). out (f32) and outbf (bf16) both optional.
// 64x256 tile, 8 waves (2M x 4N), grid 782 -> 3 blocks/CU resident.
__global__ __launch_bounds__(512) void gemm_ln_kernel(
    const u16* __restrict__ hbA, const u16* __restrict__ XB2,
    const u16* __restrict__ WT,
    const float* __restrict__ bvec, const float* __restrict__ bem,
    const int* __restrict__ rs,
    const float* __restrict__ g, const float* __restrict__ beta,
    float* __restrict__ out, u16* __restrict__ outbf, int n) {
    __shared__ u16 Al[2 * BM * KC];          // 8 KB
    __shared__ u16 Bl[2 * DDIM * KC];        // 32 KB
    __shared__ float2 mom[BM][4];            // 2 KB
    __shared__ float indls[BM];

    const int t = threadIdx.x;
    const int wid = t >> 6, lane = t & 63, lo = lane & 15, hi = lane >> 4;
    const int wr = wid >> 2, wc = wid & 3;   // 2M x 4N
    const int n0 = blockIdx.x * BM;

    if (t < BM) {
        int r = n0 + t;
        indls[t] = (r < n && (rs[r + 1] - rs[r]) > 0) ? 1.0f : 0.0f;
    }

    // A staging (first 4 waves; 256 lanes cover 64 rows x 4 slots)
    const int arow = (t & 255) >> 2;
    const int aslot = (t & 3) ^ ((arow >> 1) & 3);   // inverse-swizzled source
    const u16* agA = hbA + (size_t)(n0 + arow) * DDIM + aslot * 8;
    const u16* agX = XB2 + (size_t)(n0 + arow) * XA + aslot * 8;
    // B staging (all 8 waves, 2 loads each)
    const int br0 = t >> 2;
    const int bs0 = (t & 3) ^ ((br0 >> 1) & 3);
    const u16* bgp0 = WT + (size_t)br0 * XK + bs0 * 8;
    const int br1 = 128 + (t >> 2);
    const int bs1 = (t & 3) ^ ((br1 >> 1) & 3);
    const u16* bgp1 = WT + (size_t)br1 * XK + bs1 * 8;

    f32x4 acc[2][4];
#pragma unroll
    for (int i = 0; i < 2; ++i)
#pragma unroll
        for (int j = 0; j < 4; ++j) acc[i][j] = {0.f, 0.f, 0.f, 0.f};

    auto STAGE = [&](int buf, int kk) {
        if (wid < 4) {
            const u16* ap = (kk < 8) ? (agA + kk * KC) : (agX + (kk - 8) * KC);
            GLOAD16(ap, &Al[buf * 2048 + wid * 512]);
        }
        int k0 = kk * KC;
        GLOAD16(bgp0 + k0, &Bl[buf * 8192 + wid * 512]);
        GLOAD16(bgp1 + k0, &Bl[buf * 8192 + 4096 + wid * 512]);
    };

    STAGE(0, 0);
    __syncthreads();

    for (int ks = 0; ks < KSTEPS; ++ks) {
        int cur = ks & 1;
        if (ks < KSTEPS - 1) STAGE(1 - cur, ks + 1);

        s16x8 af[2], bf[4];
#pragma unroll
        for (int rt = 0; rt < 2; ++rt) {
            int row = wr * 32 + rt * 16 + lo;
            af[rt] = *reinterpret_cast<const s16x8*>(
                &Al[cur * 2048 + row * KC + ((hi ^ ((row >> 1) & 3)) << 3)]);
        }
#pragma unroll
        for (int ct = 0; ct < 4; ++ct) {
            int c = wc * 64 + ct * 16 + lo;
            bf[ct] = *reinterpret_cast<const s16x8*>(
                &Bl[cur * 8192 + c * KC + ((hi ^ ((c >> 1) & 3)) << 3)]);
        }
#pragma unroll
        for (int rt = 0; rt < 2; ++rt)
#pragma unroll
            for (int ct = 0; ct < 4; ++ct)
                acc[rt][ct] = __builtin_amdgcn_mfma_f32_16x16x32_bf16(
                    af[rt], bf[ct], acc[rt][ct], 0, 0, 0);

        __syncthreads();
    }

    float bb[4], bbem[4], gv[4], bev[4];
#pragma unroll
    for (int ct = 0; ct < 4; ++ct) {
        int c = wc * 64 + ct * 16 + lo;
        bb[ct] = bvec[c]; bbem[ct] = bem[c]; gv[ct] = g[c]; bev[ct] = beta[c];
    }
#pragma unroll
    for (int rt = 0; rt < 2; ++rt)
#pragma unroll
        for (int reg = 0; reg < 4; ++reg) {
            float indv = indls[wr * 32 + rt * 16 + hi * 4 + reg];
#pragma unroll
            for (int ct = 0; ct < 4; ++ct)
                acc[rt][ct][reg] += bb[ct] + indv * bbem[ct];
        }

#pragma unroll
    for (int rt = 0; rt < 2; ++rt)
#pragma unroll
        for (int reg = 0; reg < 4; ++reg) {
            float s = acc[rt][0][reg] + acc[rt][1][reg] + acc[rt][2][reg] + acc[rt][3][reg];
            float q = acc[rt][0][reg] * acc[rt][0][reg] + acc[rt][1][reg] * acc[rt][1][reg]
                    + acc[rt][2][reg] * acc[rt][2][reg] + acc[rt][3][reg] * acc[rt][3][reg];
#pragma unroll
            for (int m = 1; m < 16; m <<= 1) {
                s += __shfl_xor(s, m);
                q += __shfl_xor(q, m);
            }
            if (lo == 0) mom[wr * 32 + rt * 16 + hi * 4 + reg][wc] = make_float2(s, q);
        }
    __syncthreads();

#pragma unroll
    for (int rt = 0; rt < 2; ++rt)
#pragma unroll
        for (int reg = 0; reg < 4; ++reg) {
            int rl = wr * 32 + rt * 16 + hi * 4 + reg;
            float2 m0 = mom[rl][0], m1 = mom[rl][1], m2 = mom[rl][2], m3 = mom[rl][3];
            float s = m0.x + m1.x + m2.x + m3.x;
            float q = m0.y + m1.y + m2.y + m3.y;
            float mean = s * (1.0f / 256.0f);
            float var = q * (1.0f / 256.0f) - mean * mean;
            float inv = rsqrtf(var + 1e-5f);
            int r = n0 + rl;
            if (r < n) {
#pragma unroll
                for (int ct = 0; ct < 4; ++ct) {
                    float val = (acc[rt][ct][reg] - mean) * inv * gv[ct] + bev[ct];
                    size_t o = (size_t)r * DDIM + wc * 64 + ct * 16 + lo;
                    if (out) out[o] = val;
                    if (outbf) outbf[o] = f2bf(val);
                }
            }
        }
}

static inline size_t alignup(size_t x) { return (x + 1023) & ~(size_t)1023; }

extern "C" void kernel_launch(void* const* d_in, const int* in_sizes, int n_in,
                              void* d_out, int out_size, void* d_ws, size_t ws_size,
                              hipStream_t stream) {
    const float* h_user  = (const float*)d_in[0];
    const float* h_item  = (const float*)d_in[1];
    const float* et_ub   = (const float*)d_in[2];
    const float* et_bu   = (const float*)d_in[3];
    const float* W0_ub   = (const float*)d_in[4];
    const float* b0_ub   = (const float*)d_in[5];
    const float* W0_bu   = (const float*)d_in[6];
    const float* b0_bu   = (const float*)d_in[7];
    const float* W1_ub   = (const float*)d_in[8];
    const float* b1_ub   = (const float*)d_in[9];
    const float* W1_bu   = (const float*)d_in[10];
    const float* b1_bu   = (const float*)d_in[11];
    const float* bem_ub  = (const float*)d_in[13];
    const float* bem_bu  = (const float*)d_in[15];
    const float* g_u     = (const float*)d_in[16];
    const float* beta_u  = (const float*)d_in[17];
    const float* g_i     = (const float*)d_in[18];
    const float* beta_i  = (const float*)d_in[19];
    const int*   ei_ub   = (const int*)d_in[20];
    const int*   ei_bu   = (const int*)d_in[21];

    const int E = in_sizes[20] / 2;        // 500000
    const int n = in_sizes[0] / DDIM;      // 50000
    const int nPad = ((n + 127) / 128) * 128;   // padded rows for XB2
    const int nb = (n + SCHUNK - 1) / SCHUNK;   // 49

    char* w = (char*)d_ws;
    size_t off = 0;
    auto take = [&](size_t bytes) -> void* {
        void* p = w + off;
        off = alignup(off + bytes);
        return p;
    };
    int*   cnt_ub   = (int*)take((size_t)n * 4);
    int*   cnt_bu   = (int*)take((size_t)n * 4);
    size_t zero_bytes = off;                     // only counts need zeroing
    int*   rs_ub    = (int*)take((size_t)(n + 1) * 4);
    int*   rs_bu    = (int*)take((size_t)(n + 1) * 4);
    int*   cur_ub   = (int*)take((size_t)n * 4);
    int*   cur_bu   = (int*)take((size_t)n * 4);
    int*   bsum     = (int*)take((size_t)2 * 64 * 4);
    int*   ssrc_ub  = (int*)take((size_t)E * 4);
    int*   ssrc_bu  = (int*)take((size_t)E * 4);
    int*   eid_ub   = (int*)take((size_t)E * 4);
    int*   eid_bu   = (int*)take((size_t)E * 4);
    u16*   hbu0     = (u16*)take((size_t)nPad * DDIM * 2);
    u16*   hbi0     = (u16*)take((size_t)nPad * DDIM * 2);
    u16*   hbu1     = (u16*)take((size_t)nPad * DDIM * 2);
    u16*   hbi1     = (u16*)take((size_t)nPad * DDIM * 2);
    u16*   etm_ub   = (u16*)take((size_t)n * EDIM * 2);
    u16*   etm_bu   = (u16*)take((size_t)n * EDIM * 2);
    u16*   XB2      = (u16*)take((size_t)nPad * XA * 2);
    u16*   WT       = (u16*)take((size_t)4 * DDIM * XK * 2);
    (void)ws_size; (void)n_in; (void)out_size;

    const int* src_ub = ei_ub;
    const int* dst_ub = ei_ub + E;
    const int* src_bu = ei_bu;
    const int* dst_bu = ei_bu + E;

    hipMemsetAsync(w, 0, zero_bytes, stream);

    int eb = (E + 255) / 256;
    count_kernel<<<eb, 256, 0, stream>>>(dst_ub, E, cnt_ub);
    count_kernel<<<eb, 256, 0, stream>>>(dst_bu, E, cnt_bu);
    dim3 sg(nb, 2);
    scan_partial_kernel<<<sg, 256, 0, stream>>>(cnt_ub, cnt_bu, n, bsum, nb);
    scan_bsum_kernel<<<1, 128, 0, stream>>>(bsum, nb, rs_ub, rs_bu, n);
    scan_final_kernel<<<sg, 256, 0, stream>>>(cnt_ub, cnt_bu, n, bsum, nb,
                                              rs_ub, cur_ub, rs_bu, cur_bu);
    fill_kernel<<<eb, 256, 0, stream>>>(src_ub, dst_ub, E, cur_ub, ssrc_ub, eid_ub);
    fill_kernel<<<eb, 256, 0, stream>>>(src_bu, dst_bu, E, cur_bu, ssrc_bu, eid_bu);
    int ngb = (n + 3) / 4;
    etgather_kernel<<<ngb, 256, 0, stream>>>(et_ub, rs_ub, eid_ub, etm_ub, n);
    etgather_kernel<<<ngb, 256, 0, stream>>>(et_bu, rs_bu, eid_bu, etm_bu, n);

    dim3 wtg(XK, 4);
    wt_build_kernel<<<wtg, 256, 0, stream>>>(W0_ub, W0_bu, W1_ub, W1_bu,
                                             (const float*)d_in[12], (const float*)d_in[14], WT);

    float* hu_out = (float*)d_out;
    float* hi_out = (float*)d_out + (size_t)n * DDIM;
    int total4 = n * DDIM / 4;
    int cvb = 2048;
    int gb = (n + BM - 1) / BM;              // 782
    const u16* WT0 = WT;
    const u16* WT1 = WT + (size_t)DDIM * XK;
    const u16* WT2 = WT + (size_t)2 * DDIM * XK;
    const u16* WT3 = WT + (size_t)3 * DDIM * XK;

    // ---- layer 0: bf16-only outputs into fresh buffers (no aliasing) ----
    conv_h_kernel<<<cvb, 256, 0, stream>>>(h_user, hbu0, total4);
    conv_h_kernel<<<cvb, 256, 0, stream>>>(h_item, hbi0, total4);
    build_x_kernel<<<ngb, 256, 0, stream>>>(hbu0, rs_ub, ssrc_ub, etm_ub, XB2, n);
    gemm_ln_kernel<<<gb, 512, 0, stream>>>(hbi0, XB2, WT0, b0_ub, bem_ub, rs_ub,
                                           g_i, beta_i, nullptr, hbi1, n);
    build_x_kernel<<<ngb, 256, 0, stream>>>(hbi0, rs_bu, ssrc_bu, etm_bu, XB2, n);
    gemm_ln_kernel<<<gb, 512, 0, stream>>>(hbu0, XB2, WT1, b0_bu, bem_bu, rs_bu,
                                           g_u, beta_u, nullptr, hbu1, n);

    // ---- layer 1: f32 outputs to d_out ----
    build_x_kernel<<<ngb, 256, 0, stream>>>(hbu1, rs_ub, ssrc_ub, etm_ub, XB2, n);
    gemm_ln_kernel<<<gb, 512, 0, stream>>>(hbi1, XB2, WT2, b1_ub, bem_ub, rs_ub,
                                           g_i, beta_i, hi_out, nullptr, n);
    build_x_kernel<<<ngb, 256, 0, stream>>>(hbi1, rs_bu, ssrc_bu, etm_bu, XB2, n);
    gemm_ln_kernel<<<gb, 512, 0, stream>>>(hbu1, XB2, WT3, b1_bu, bem_bu, rs_bu,
                                           g_u, beta_u, hu_out, nullptr, n);
}

// Round 7
// 536.733 us; speedup vs baseline: 5.2437x; 1.1049x over previous
//
#include <hip/hip_runtime.h>

// HetSAGE: 2-layer heterogeneous GraphSAGE, N=50000/type, E=500000/type, D=256.
// R6: merge per-edge-type kernel pairs into single launches (blockIdx.y picks
// the type) -> 13 dispatches instead of 21, better tail/occupancy mixing;
// build_x load batching 4->8; two XB2 buffers remove intra-grid hazards.

#define DDIM 256
#define EDIM 32
#define XK 544          // WT row stride (total K)
#define XA 288          // XB2 row stride: 256 agg + 32 et
#define BM 64           // GEMM row tile
#define KC 32           // K chunk
#define KSTEPS 17       // 544/32
#define SCHUNK 1024     // scan elements per block

typedef unsigned short u16;
typedef short s16x8 __attribute__((ext_vector_type(8)));
typedef float f32x4 __attribute__((ext_vector_type(4)));
typedef u16 u16x4 __attribute__((ext_vector_type(4)));

__device__ __forceinline__ u16 f2bf(float f) {
    unsigned u = __builtin_bit_cast(unsigned, f);
    u += 0x7FFF + ((u >> 16) & 1);           // RNE
    return (u16)(u >> 16);
}
__device__ __forceinline__ float bf2f(u16 u) {
    unsigned x = ((unsigned)u) << 16;
    return __builtin_bit_cast(float, x);
}

#define GLOAD16(gp, lp)                                                        \
    __builtin_amdgcn_global_load_lds(                                          \
        (const __attribute__((address_space(1))) unsigned int*)(gp),           \
        (__attribute__((address_space(3))) unsigned int*)(lp), 16, 0, 0)

// ---------------- CSR build (merged: blockIdx.y = edge type) ----------------
__global__ void count_kernel(const int* __restrict__ d0, const int* __restrict__ d1,
                             int E, int* __restrict__ c0, int* __restrict__ c1) {
    const int* dst = blockIdx.y ? d1 : d0;
    int* cnt = blockIdx.y ? c1 : c0;
    int e = blockIdx.x * blockDim.x + threadIdx.x;
    if (e < E) atomicAdd(&cnt[dst[e]], 1);
}

__global__ void scan_partial_kernel(const int* __restrict__ cnt0, const int* __restrict__ cnt1,
                                    int n, int* __restrict__ bsum, int nb) {
    const int* cnt = blockIdx.y ? cnt1 : cnt0;
    int base = blockIdx.x * SCHUNK + threadIdx.x * 4;
    int s = 0;
#pragma unroll
    for (int i = 0; i < 4; ++i) {
        int idx = base + i;
        if (idx < n) s += cnt[idx];
    }
#pragma unroll
    for (int m = 1; m < 64; m <<= 1) s += __shfl_xor(s, m);
    __shared__ int ws[4];
    int lane = threadIdx.x & 63, wid = threadIdx.x >> 6;
    if (lane == 0) ws[wid] = s;
    __syncthreads();
    if (threadIdx.x == 0) bsum[blockIdx.y * nb + blockIdx.x] = ws[0] + ws[1] + ws[2] + ws[3];
}

__global__ void scan_bsum_kernel(int* __restrict__ bsum, int nb,
                                 int* __restrict__ rs0, int* __restrict__ rs1, int n) {
    int wid = threadIdx.x >> 6, lane = threadIdx.x & 63;
    int* bs = bsum + wid * nb;
    int v = (lane < nb) ? bs[lane] : 0;
    int ps = v;
#pragma unroll
    for (int m = 1; m < 64; m <<= 1) {
        int u = __shfl_up(ps, m);
        if (lane >= m) ps += u;
    }
    if (lane < nb) bs[lane] = ps - v;   // exclusive
    if (lane == nb - 1) (wid ? rs1 : rs0)[n] = ps;
}

__global__ void scan_final_kernel(const int* __restrict__ cnt0, const int* __restrict__ cnt1,
                                  int n, const int* __restrict__ bsum, int nb,
                                  int* __restrict__ rs0, int* __restrict__ cur0,
                                  int* __restrict__ rs1, int* __restrict__ cur1) {
    const int* cnt = blockIdx.y ? cnt1 : cnt0;
    int* rs  = blockIdx.y ? rs1 : rs0;
    int* cur = blockIdx.y ? cur1 : cur0;
    int t = threadIdx.x;
    int base = blockIdx.x * SCHUNK + t * 4;
    int v[4];
    int s = 0;
#pragma unroll
    for (int i = 0; i < 4; ++i) {
        int idx = base + i;
        v[i] = (idx < n) ? cnt[idx] : 0;
        s += v[i];
    }
    int lane = t & 63, wid = t >> 6;
    int ps = s;
#pragma unroll
    for (int m = 1; m < 64; m <<= 1) {
        int u = __shfl_up(ps, m);
        if (lane >= m) ps += u;
    }
    __shared__ int wsum[4];
    if (lane == 63) wsum[wid] = ps;
    __syncthreads();
    int wofs = 0;
    for (int i = 0; i < wid; ++i) wofs += wsum[i];
    int run = bsum[blockIdx.y * nb + blockIdx.x] + wofs + ps - s;
#pragma unroll
    for (int i = 0; i < 4; ++i) {
        int idx = base + i;
        if (idx < n) {
            rs[idx] = run;
            cur[idx] = run;
            run += v[i];
        }
    }
}

__global__ void fill_kernel(const int* __restrict__ ei0, const int* __restrict__ ei1, int E,
                            int* __restrict__ cu0, int* __restrict__ cu1,
                            int* __restrict__ sr0, int* __restrict__ sr1,
                            int* __restrict__ ed0, int* __restrict__ ed1) {
    const int* src = blockIdx.y ? ei1 : ei0;
    const int* dst = (blockIdx.y ? ei1 : ei0) + E;
    int* cursor = blockIdx.y ? cu1 : cu0;
    int* ssrc   = blockIdx.y ? sr1 : sr0;
    int* eid    = blockIdx.y ? ed1 : ed0;
    int e = blockIdx.x * blockDim.x + threadIdx.x;
    if (e < E) {
        int d = dst[e];
        int p = atomicAdd(&cursor[d], 1);
        ssrc[p] = src[e];
        eid[p] = e;
    }
}

// per-node et mean via CSR; 1 node/wave, 4 waves/block; merged types.
__global__ __launch_bounds__(256) void etgather_kernel(
    const float* __restrict__ et0, const float* __restrict__ et1,
    const int* __restrict__ rs0, const int* __restrict__ rs1,
    const int* __restrict__ ed0, const int* __restrict__ ed1,
    u16* __restrict__ em0, u16* __restrict__ em1, int n) {
    const float* et = blockIdx.y ? et1 : et0;
    const int* rs  = blockIdx.y ? rs1 : rs0;
    const int* eid = blockIdx.y ? ed1 : ed0;
    u16* etmean    = blockIdx.y ? em1 : em0;
    int node = blockIdx.x * 4 + (threadIdx.x >> 6);
    if (node >= n) return;
    int lane = threadIdx.x & 63;
    int c = lane & 31, eh = lane >> 5;
    int s0 = rs[node], s1 = rs[node + 1];
    float a = 0.f;
    for (int base = s0 + eh; base < s1; base += 8) {
        int idx[4];
#pragma unroll
        for (int j = 0; j < 4; ++j) {
            int e = base + 2 * j;
            idx[j] = eid[e < s1 ? e : s0];     // clamped: always a valid slot
        }
        float v[4];
#pragma unroll
        for (int j = 0; j < 4; ++j)
            v[j] = et[(size_t)idx[j] * EDIM + c];
#pragma unroll
        for (int j = 0; j < 4; ++j)
            if (base + 2 * j < s1) a += v[j];
    }
    a += __shfl_xor(a, 32);
    if (eh == 0) {
        int cn = s1 - s0;
        float ic = 1.0f / (float)(cn > 1 ? cn : 1);
        etmean[(size_t)node * EDIM + c] = f2bf(a * ic);
    }
}

// ---------------- bf16 prep (merged: y picks table) ----------------
__global__ void conv_h_kernel(const float* __restrict__ h0, const float* __restrict__ h1,
                              u16* __restrict__ hb0, u16* __restrict__ hb1, int total4) {
    const float* h = blockIdx.y ? h1 : h0;
    u16* hb = blockIdx.y ? hb1 : hb0;
    int i = blockIdx.x * blockDim.x + threadIdx.x;
    int stride = gridDim.x * blockDim.x;
    for (; i < total4; i += stride) {
        float4 v = reinterpret_cast<const float4*>(h)[i];
        u16x4 o;
        o.x = f2bf(v.x); o.y = f2bf(v.y); o.z = f2bf(v.z); o.w = f2bf(v.w);
        reinterpret_cast<u16x4*>(hb)[i] = o;
    }
}

// WT[mat][c][k] = (k<512 ? W[k][c] : Wem[k-512][c]) as bf16
__global__ void wt_build_kernel(const float* W0, const float* W1, const float* W2,
                                const float* W3, const float* EmA, const float* EmB,
                                u16* __restrict__ WT) {
    int k = blockIdx.x;
    int mat = blockIdx.y;
    int c = threadIdx.x;
    const float* W = (mat == 0) ? W0 : (mat == 1) ? W1 : (mat == 2) ? W2 : W3;
    const float* Em = (mat & 1) ? EmB : EmA;
    float v = (k < 512) ? W[(size_t)k * DDIM + c] : Em[(size_t)(k - 512) * DDIM + c];
    WT[((size_t)mat * DDIM + c) * XK + k] = f2bf(v);
}

// XB2 row = [bf16(mean agg) | bf16 etmean]; merged types; 8-deep batching.
__global__ __launch_bounds__(256) void build_x_kernel(
    const u16* __restrict__ src0, const u16* __restrict__ src1,
    const int* __restrict__ rs0, const int* __restrict__ rs1,
    const int* __restrict__ ss0, const int* __restrict__ ss1,
    const u16* __restrict__ em0, const u16* __restrict__ em1,
    u16* __restrict__ xb0, u16* __restrict__ xb1, int n) {
    const u16* hbsrc = blockIdx.y ? src1 : src0;
    const int* rs    = blockIdx.y ? rs1 : rs0;
    const int* ssrc  = blockIdx.y ? ss1 : ss0;
    const u16* etmean= blockIdx.y ? em1 : em0;
    u16* XB2         = blockIdx.y ? xb1 : xb0;
    int node = blockIdx.x * 4 + (threadIdx.x >> 6);
    if (node >= n) return;
    int t = threadIdx.x & 63;
    int s0 = rs[node], s1 = rs[node + 1];
    int cdeg = s1 - s0;
    float ic = 1.0f / (float)(cdeg > 1 ? cdeg : 1);
    float a0 = 0.f, a1 = 0.f, a2 = 0.f, a3 = 0.f;
    for (int base = s0; base < s1; base += 8) {
        int si[8];
#pragma unroll
        for (int j = 0; j < 8; ++j) {
            int e = base + j;
            si[j] = ssrc[e < s1 ? e : s0];     // clamped valid slot
        }
        u16x4 v[8];
#pragma unroll
        for (int j = 0; j < 8; ++j)
            v[j] = *reinterpret_cast<const u16x4*>(&hbsrc[(size_t)si[j] * DDIM + t * 4]);
#pragma unroll
        for (int j = 0; j < 8; ++j)
            if (base + j < s1) {
                a0 += bf2f(v[j].x); a1 += bf2f(v[j].y);
                a2 += bf2f(v[j].z); a3 += bf2f(v[j].w);
            }
    }
    u16* xr = XB2 + (size_t)node * XA;
    u16x4 o;
    o.x = f2bf(a0 * ic); o.y = f2bf(a1 * ic); o.z = f2bf(a2 * ic); o.w = f2bf(a3 * ic);
    *reinterpret_cast<u16x4*>(&xr[t * 4]) = o;
    if (t < 8)
        reinterpret_cast<u16x4*>(&xr[DDIM])[t] =
            reinterpret_cast<const u16x4*>(&etmean[(size_t)node * EDIM])[t];
}

// ---------------- MFMA GEMM + bias + LayerNorm (merged types) ----------------
// A: chunks 0..7 from hbA (self), 8..16 from XB2 ([agg|et], stride 288).
// 64x256 tile, 8 waves; grid (782, 2).
__global__ __launch_bounds__(512) void gemm_ln_kernel(
    const u16* __restrict__ hbA0, const u16* __restrict__ hbA1,
    const u16* __restrict__ X0, const u16* __restrict__ X1,
    const u16* __restrict__ WTa, const u16* __restrict__ WTb,
    const float* __restrict__ bv0, const float* __restrict__ bv1,
    const float* __restrict__ bm0, const float* __restrict__ bm1,
    const int* __restrict__ rs0, const int* __restrict__ rs1,
    const float* __restrict__ g0, const float* __restrict__ g1,
    const float* __restrict__ be0, const float* __restrict__ be1,
    float* __restrict__ out0, float* __restrict__ out1,
    u16* __restrict__ obf0, u16* __restrict__ obf1, int n) {
    const int ty = blockIdx.y;
    const u16* hbA = ty ? hbA1 : hbA0;
    const u16* XB2 = ty ? X1 : X0;
    const u16* WT  = ty ? WTb : WTa;
    const float* bvec = ty ? bv1 : bv0;
    const float* bem  = ty ? bm1 : bm0;
    const int* rs     = ty ? rs1 : rs0;
    const float* g    = ty ? g1 : g0;
    const float* beta = ty ? be1 : be0;
    float* out  = ty ? out1 : out0;
    u16* outbf  = ty ? obf1 : obf0;

    __shared__ u16 Al[2 * BM * KC];          // 8 KB
    __shared__ u16 Bl[2 * DDIM * KC];        // 32 KB
    __shared__ float2 mom[BM][4];            // 2 KB
    __shared__ float indls[BM];

    const int t = threadIdx.x;
    const int wid = t >> 6, lane = t & 63, lo = lane & 15, hi = lane >> 4;
    const int wr = wid >> 2, wc = wid & 3;   // 2M x 4N
    const int n0 = blockIdx.x * BM;

    if (t < BM) {
        int r = n0 + t;
        indls[t] = (r < n && (rs[r + 1] - rs[r]) > 0) ? 1.0f : 0.0f;
    }

    const int arow = (t & 255) >> 2;
    const int aslot = (t & 3) ^ ((arow >> 1) & 3);   // inverse-swizzled source
    const u16* agA = hbA + (size_t)(n0 + arow) * DDIM + aslot * 8;
    const u16* agX = XB2 + (size_t)(n0 + arow) * XA + aslot * 8;
    const int br0 = t >> 2;
    const int bs0 = (t & 3) ^ ((br0 >> 1) & 3);
    const u16* bgp0 = WT + (size_t)br0 * XK + bs0 * 8;
    const int br1 = 128 + (t >> 2);
    const int bs1 = (t & 3) ^ ((br1 >> 1) & 3);
    const u16* bgp1 = WT + (size_t)br1 * XK + bs1 * 8;

    f32x4 acc[2][4];
#pragma unroll
    for (int i = 0; i < 2; ++i)
#pragma unroll
        for (int j = 0; j < 4; ++j) acc[i][j] = {0.f, 0.f, 0.f, 0.f};

    auto STAGE = [&](int buf, int kk) {
        if (wid < 4) {
            const u16* ap = (kk < 8) ? (agA + kk * KC) : (agX + (kk - 8) * KC);
            GLOAD16(ap, &Al[buf * 2048 + wid * 512]);
        }
        int k0 = kk * KC;
        GLOAD16(bgp0 + k0, &Bl[buf * 8192 + wid * 512]);
        GLOAD16(bgp1 + k0, &Bl[buf * 8192 + 4096 + wid * 512]);
    };

    STAGE(0, 0);
    __syncthreads();

    for (int ks = 0; ks < KSTEPS; ++ks) {
        int cur = ks & 1;
        if (ks < KSTEPS - 1) STAGE(1 - cur, ks + 1);

        s16x8 af[2], bf[4];
#pragma unroll
        for (int rt = 0; rt < 2; ++rt) {
            int row = wr * 32 + rt * 16 + lo;
            af[rt] = *reinterpret_cast<const s16x8*>(
                &Al[cur * 2048 + row * KC + ((hi ^ ((row >> 1) & 3)) << 3)]);
        }
#pragma unroll
        for (int ct = 0; ct < 4; ++ct) {
            int c = wc * 64 + ct * 16 + lo;
            bf[ct] = *reinterpret_cast<const s16x8*>(
                &Bl[cur * 8192 + c * KC + ((hi ^ ((c >> 1) & 3)) << 3)]);
        }
#pragma unroll
        for (int rt = 0; rt < 2; ++rt)
#pragma unroll
            for (int ct = 0; ct < 4; ++ct)
                acc[rt][ct] = __builtin_amdgcn_mfma_f32_16x16x32_bf16(
                    af[rt], bf[ct], acc[rt][ct], 0, 0, 0);

        __syncthreads();
    }

    float bb[4], bbem[4], gv[4], bev[4];
#pragma unroll
    for (int ct = 0; ct < 4; ++ct) {
        int c = wc * 64 + ct * 16 + lo;
        bb[ct] = bvec[c]; bbem[ct] = bem[c]; gv[ct] = g[c]; bev[ct] = beta[c];
    }
#pragma unroll
    for (int rt = 0; rt < 2; ++rt)
#pragma unroll
        for (int reg = 0; reg < 4; ++reg) {
            float indv = indls[wr * 32 + rt * 16 + hi * 4 + reg];
#pragma unroll
            for (int ct = 0; ct < 4; ++ct)
                acc[rt][ct][reg] += bb[ct] + indv * bbem[ct];
        }

#pragma unroll
    for (int rt = 0; rt < 2; ++rt)
#pragma unroll
        for (int reg = 0; reg < 4; ++reg) {
            float s = acc[rt][0][reg] + acc[rt][1][reg] + acc[rt][2][reg] + acc[rt][3][reg];
            float q = acc[rt][0][reg] * acc[rt][0][reg] + acc[rt][1][reg] * acc[rt][1][reg]
                    + acc[rt][2][reg] * acc[rt][2][reg] + acc[rt][3][reg] * acc[rt][3][reg];
#pragma unroll
            for (int m = 1; m < 16; m <<= 1) {
                s += __shfl_xor(s, m);
                q += __shfl_xor(q, m);
            }
            if (lo == 0) mom[wr * 32 + rt * 16 + hi * 4 + reg][wc] = make_float2(s, q);
        }
    __syncthreads();

#pragma unroll
    for (int rt = 0; rt < 2; ++rt)
#pragma unroll
        for (int reg = 0; reg < 4; ++reg) {
            int rl = wr * 32 + rt * 16 + hi * 4 + reg;
            float2 m0 = mom[rl][0], m1 = mom[rl][1], m2 = mom[rl][2], m3 = mom[rl][3];
            float s = m0.x + m1.x + m2.x + m3.x;
            float q = m0.y + m1.y + m2.y + m3.y;
            float mean = s * (1.0f / 256.0f);
            float var = q * (1.0f / 256.0f) - mean * mean;
            float inv = rsqrtf(var + 1e-5f);
            int r = n0 + rl;
            if (r < n) {
#pragma unroll
                for (int ct = 0; ct < 4; ++ct) {
                    float val = (acc[rt][ct][reg] - mean) * inv * gv[ct] + bev[ct];
                    size_t o = (size_t)r * DDIM + wc * 64 + ct * 16 + lo;
                    if (out) out[o] = val;
                    if (outbf) outbf[o] = f2bf(val);
                }
            }
        }
}

static inline size_t alignup(size_t x) { return (x + 1023) & ~(size_t)1023; }

extern "C" void kernel_launch(void* const* d_in, const int* in_sizes, int n_in,
                              void* d_out, int out_size, void* d_ws, size_t ws_size,
                              hipStream_t stream) {
    const float* h_user  = (const float*)d_in[0];
    const float* h_item  = (const float*)d_in[1];
    const float* et_ub   = (const float*)d_in[2];
    const float* et_bu   = (const float*)d_in[3];
    const float* W0_ub   = (const float*)d_in[4];
    const float* b0_ub   = (const float*)d_in[5];
    const float* W0_bu   = (const float*)d_in[6];
    const float* b0_bu   = (const float*)d_in[7];
    const float* W1_ub   = (const float*)d_in[8];
    const float* b1_ub   = (const float*)d_in[9];
    const float* W1_bu   = (const float*)d_in[10];
    const float* b1_bu   = (const float*)d_in[11];
    const float* bem_ub  = (const float*)d_in[13];
    const float* bem_bu  = (const float*)d_in[15];
    const float* g_u     = (const float*)d_in[16];
    const float* beta_u  = (const float*)d_in[17];
    const float* g_i     = (const float*)d_in[18];
    const float* beta_i  = (const float*)d_in[19];
    const int*   ei_ub   = (const int*)d_in[20];
    const int*   ei_bu   = (const int*)d_in[21];

    const int E = in_sizes[20] / 2;        // 500000
    const int n = in_sizes[0] / DDIM;      // 50000
    const int nPad = ((n + 127) / 128) * 128;
    const int nb = (n + SCHUNK - 1) / SCHUNK;   // 49

    char* w = (char*)d_ws;
    size_t off = 0;
    auto take = [&](size_t bytes) -> void* {
        void* p = w + off;
        off = alignup(off + bytes);
        return p;
    };
    int*   cnt_ub   = (int*)take((size_t)n * 4);
    int*   cnt_bu   = (int*)take((size_t)n * 4);
    size_t zero_bytes = off;                     // only counts need zeroing
    int*   rs_ub    = (int*)take((size_t)(n + 1) * 4);
    int*   rs_bu    = (int*)take((size_t)(n + 1) * 4);
    int*   cur_ub   = (int*)take((size_t)n * 4);
    int*   cur_bu   = (int*)take((size_t)n * 4);
    int*   bsum     = (int*)take((size_t)2 * 64 * 4);
    int*   ssrc_ub  = (int*)take((size_t)E * 4);
    int*   ssrc_bu  = (int*)take((size_t)E * 4);
    int*   eid_ub   = (int*)take((size_t)E * 4);
    int*   eid_bu   = (int*)take((size_t)E * 4);
    u16*   hbu0     = (u16*)take((size_t)nPad * DDIM * 2);
    u16*   hbi0     = (u16*)take((size_t)nPad * DDIM * 2);
    u16*   hbu1     = (u16*)take((size_t)nPad * DDIM * 2);
    u16*   hbi1     = (u16*)take((size_t)nPad * DDIM * 2);
    u16*   etm_ub   = (u16*)take((size_t)n * EDIM * 2);
    u16*   etm_bu   = (u16*)take((size_t)n * EDIM * 2);
    u16*   XB2a     = (u16*)take((size_t)nPad * XA * 2);
    u16*   XB2b     = (u16*)take((size_t)nPad * XA * 2);
    u16*   WT       = (u16*)take((size_t)4 * DDIM * XK * 2);
    (void)ws_size; (void)n_in; (void)out_size;

    hipMemsetAsync(w, 0, zero_bytes, stream);

    int eb = (E + 255) / 256;
    count_kernel<<<dim3(eb, 2), 256, 0, stream>>>(ei_ub + E, ei_bu + E, E, cnt_ub, cnt_bu);
    dim3 sg(nb, 2);
    scan_partial_kernel<<<sg, 256, 0, stream>>>(cnt_ub, cnt_bu, n, bsum, nb);
    scan_bsum_kernel<<<1, 128, 0, stream>>>(bsum, nb, rs_ub, rs_bu, n);
    scan_final_kernel<<<sg, 256, 0, stream>>>(cnt_ub, cnt_bu, n, bsum, nb,
                                              rs_ub, cur_ub, rs_bu, cur_bu);
    fill_kernel<<<dim3(eb, 2), 256, 0, stream>>>(ei_ub, ei_bu, E, cur_ub, cur_bu,
                                                 ssrc_ub, ssrc_bu, eid_ub, eid_bu);
    int ngb = (n + 3) / 4;
    etgather_kernel<<<dim3(ngb, 2), 256, 0, stream>>>(et_ub, et_bu, rs_ub, rs_bu,
                                                      eid_ub, eid_bu, etm_ub, etm_bu, n);

    dim3 wtg(XK, 4);
    wt_build_kernel<<<wtg, 256, 0, stream>>>(W0_ub, W0_bu, W1_ub, W1_bu,
                                             (const float*)d_in[12], (const float*)d_in[14], WT);

    float* hu_out = (float*)d_out;
    float* hi_out = (float*)d_out + (size_t)n * DDIM;
    int total4 = n * DDIM / 4;
    int gb = (n + BM - 1) / BM;              // 782
    const u16* WT0 = WT;
    const u16* WT1 = WT + (size_t)DDIM * XK;
    const u16* WT2 = WT + (size_t)2 * DDIM * XK;
    const u16* WT3 = WT + (size_t)3 * DDIM * XK;

    conv_h_kernel<<<dim3(1024, 2), 256, 0, stream>>>(h_user, h_item, hbu0, hbi0, total4);

    // ---- layer 0 (bf16-only outputs into fresh buffers) ----
    // y=0: item update (agg users via ub-CSR); y=1: user update (agg items).
    build_x_kernel<<<dim3(ngb, 2), 256, 0, stream>>>(hbu0, hbi0, rs_ub, rs_bu,
                                                     ssrc_ub, ssrc_bu, etm_ub, etm_bu,
                                                     XB2a, XB2b, n);
    gemm_ln_kernel<<<dim3(gb, 2), 512, 0, stream>>>(
        hbi0, hbu0, XB2a, XB2b, WT0, WT1, b0_ub, b0_bu, bem_ub, bem_bu,
        rs_ub, rs_bu, g_i, g_u, beta_i, beta_u,
        nullptr, nullptr, hbi1, hbu1, n);

    // ---- layer 1 (f32 outputs to d_out) ----
    build_x_kernel<<<dim3(ngb, 2), 256, 0, stream>>>(hbu1, hbi1, rs_ub, rs_bu,
                                                     ssrc_ub, ssrc_bu, etm_ub, etm_bu,
                                                     XB2a, XB2b, n);
    gemm_ln_kernel<<<dim3(gb, 2), 512, 0, stream>>>(
        hbi1, hbu1, XB2a, XB2b, WT2, WT3, b1_ub, b1_bu, bem_ub, bem_bu,
        rs_ub, rs_bu, g_i, g_u, beta_i, beta_u,
        hi_out, hu_out, nullptr, nullptr, n);
}